// Round 9
// baseline (226.365 us; speedup 1.0000x reference)
//
#include <hip/hip_runtime.h>
#include <hip/hip_bf16.h>
#include <math.h>

#define N_NODES 100000
#define N_EDGES 1600000
#define D 64
#define TWO_D 128
#define LN_EPS 1e-5f

#define BSHIFT 7                                   // 128 nodes per bucket
#define BMASK 127
#define NBUCK ((N_NODES + 127) >> BSHIFT)          // 782
#define BCAP 4096                                  // per-bucket CSR capacity (mean 2046, +45 sigma)
#define EPB 8192                                   // edges per bscat block
#define NEB ((N_EDGES + EPB - 1) / EPB)            // 196
#define BOFS_STRIDE (NBUCK + 1)

typedef __attribute__((ext_vector_type(4))) float f32x4;
typedef __attribute__((ext_vector_type(8))) short bf16x8;
typedef __attribute__((ext_vector_type(8))) unsigned short u16x8;

__device__ __forceinline__ float b2f(unsigned short u) {
    return __uint_as_float(((unsigned)u) << 16);
}
__device__ __forceinline__ unsigned short f2b(float f) {
    __hip_bfloat16 h = __float2bfloat16(f);   // RNE
    return __builtin_bit_cast(unsigned short, h);
}
// Order-preserving bf16 <-> u16 key (unsigned compare == float compare).
__device__ __forceinline__ unsigned short key1(unsigned short u) {
    return (u & 0x8000) ? (unsigned short)~u : (unsigned short)(u ^ 0x8000);
}
__device__ __forceinline__ unsigned short unkey1(unsigned short k) {
    return (k & 0x8000) ? (unsigned short)(k ^ 0x8000) : (unsigned short)~k;
}
__device__ __forceinline__ u16x8 pkmax8(u16x8 a, u16x8 b) {
    return __builtin_elementwise_max(a, b);       // v_pk_max_u16 x4
}

// ---------------------------------------------------------------------------
// bscat: per-block FULL LDS sort by bucket; coalesced global writes; no
// global atomics. Emits sorted chunk + per-(block,bucket) exclusive offsets.
// Edge record packed to int32: (src << 7) | (dst & 127); src < 2^17.
// ---------------------------------------------------------------------------
__global__ __launch_bounds__(1024) void bscat_kernel(const int* __restrict__ src,
                                                     const int* __restrict__ dst,
                                                     int* __restrict__ ebuf,
                                                     int* __restrict__ bofs) {
    __shared__ int cnt[NBUCK];
    __shared__ int off[NBUCK];
    __shared__ int stage[EPB];
    const int e0 = blockIdx.x * EPB;
    const int nE = min(EPB, N_EDGES - e0);
    int d[8], s[8];

    for (int i = threadIdx.x; i < NBUCK; i += 1024) cnt[i] = 0;
    __syncthreads();
#pragma unroll
    for (int k = 0; k < 8; ++k) {
        const int i = threadIdx.x + k * 1024;
        if (i < nE) {
            d[k] = dst[e0 + i];
            s[k] = src[e0 + i];
            atomicAdd(&cnt[d[k] >> BSHIFT], 1);
        }
    }
    __syncthreads();
    // Hillis-Steele inclusive scan over NBUCK (<1024)
    const int v = (threadIdx.x < NBUCK) ? cnt[threadIdx.x] : 0;
    if (threadIdx.x < NBUCK) off[threadIdx.x] = v;
    __syncthreads();
    for (int o = 1; o < 1024; o <<= 1) {
        int t = 0;
        if (threadIdx.x < NBUCK && threadIdx.x >= o) t = off[threadIdx.x - o];
        __syncthreads();
        if (threadIdx.x < NBUCK) off[threadIdx.x] += t;
        __syncthreads();
    }
    if (threadIdx.x < NBUCK) {
        const int ex = off[threadIdx.x] - v;      // exclusive
        bofs[blockIdx.x * BOFS_STRIDE + threadIdx.x] = ex;
        off[threadIdx.x] = ex;
        cnt[threadIdx.x] = 0;
    }
    if (threadIdx.x == 0) bofs[blockIdx.x * BOFS_STRIDE + NBUCK] = nE;
    __syncthreads();
#pragma unroll
    for (int k = 0; k < 8; ++k) {
        const int i = threadIdx.x + k * 1024;
        if (i < nE) {
            const int b = d[k] >> BSHIFT;
            const int r = atomicAdd(&cnt[b], 1);
            stage[off[b] + r] = (s[k] << BSHIFT) | (d[k] & BMASK);
        }
    }
    __syncthreads();
    for (int i = threadIdx.x; i < nE; i += 1024)
        ebuf[e0 + i] = stage[i];
}

// ---------------------------------------------------------------------------
// bbuild: one block per bucket. Gathers the bucket's runs from all 196 sorted
// chunks into LDS, counting-sorts by node-within-bucket, emits padded CSR.
// ---------------------------------------------------------------------------
__global__ __launch_bounds__(512) void bbuild_kernel(const int* __restrict__ ebuf,
                                                     const int* __restrict__ bofs,
                                                     int* __restrict__ row_ptr,
                                                     int* __restrict__ deg,
                                                     int* __restrict__ ssrc) {
    __shared__ int rst[NEB], rlen[NEB], rdst[NEB];
    __shared__ int stage[BCAP];
    __shared__ int stage2[BCAP];
    __shared__ int cnt[128], excl[128];
    const int b = blockIdx.x;
    const int nb0 = b << BSHIFT;

    for (int i = threadIdx.x; i < NEB; i += 512) {
        const int st = bofs[i * BOFS_STRIDE + b];
        const int en = bofs[i * BOFS_STRIDE + b + 1];
        rst[i] = st; rlen[i] = en - st;
    }
    __syncthreads();
    // scan rlen -> rdst (inclusive), NEB=196 < 256
    const int rv = (threadIdx.x < NEB) ? rlen[threadIdx.x] : 0;
    if (threadIdx.x < NEB) rdst[threadIdx.x] = rv;
    __syncthreads();
    for (int o = 1; o < 256; o <<= 1) {
        int t = 0;
        if (threadIdx.x < NEB && threadIdx.x >= o) t = rdst[threadIdx.x - o];
        __syncthreads();
        if (threadIdx.x < NEB) rdst[threadIdx.x] += t;
        __syncthreads();
    }
    const int total = rdst[NEB - 1];

    // gather runs: wave w handles regions w, w+8, ...
    const int wave = threadIdx.x >> 6, lane = threadIdx.x & 63;
    for (int i = wave; i < NEB; i += 8) {
        const int st = rst[i], len = rlen[i], doff = rdst[i] - len;
        for (int l = lane; l < len; l += 64)
            stage[doff + l] = ebuf[i * EPB + st + l];
    }
    if (threadIdx.x < 128) cnt[threadIdx.x] = 0;
    __syncthreads();

    // counting sort by node-within-bucket
    for (int i = threadIdx.x; i < total; i += 512)
        atomicAdd(&cnt[stage[i] & BMASK], 1);
    __syncthreads();
    const int cv = (threadIdx.x < 128) ? cnt[threadIdx.x] : 0;
    if (threadIdx.x < 128) excl[threadIdx.x] = cv;
    __syncthreads();
    for (int o = 1; o < 128; o <<= 1) {
        int t = 0;
        if (threadIdx.x < 128 && threadIdx.x >= o) t = excl[threadIdx.x - o];
        __syncthreads();
        if (threadIdx.x < 128) excl[threadIdx.x] += t;
        __syncthreads();
    }
    if (threadIdx.x < 128) {
        excl[threadIdx.x] -= cv;              // exclusive
        const int node = nb0 + threadIdx.x;
        if (node < N_NODES) {
            row_ptr[node] = b * BCAP + excl[threadIdx.x];
            deg[node] = cv;
        }
        cnt[threadIdx.x] = 0;
    }
    __syncthreads();
    for (int i = threadIdx.x; i < total; i += 512) {
        const int p = stage[i];
        const int dl = p & BMASK;
        const int r = atomicAdd(&cnt[dl], 1);
        stage2[excl[dl] + r] = p >> BSHIFT;
    }
    __syncthreads();
    for (int i = threadIdx.x; i < total; i += 512)
        ssrc[b * BCAP + i] = stage2[i];
}

// ---------------------------------------------------------------------------
// Converters. x is stored as order-preserving u16 KEYS.
// ---------------------------------------------------------------------------
__global__ __launch_bounds__(256) void cvt_x_kernel(const float* __restrict__ xf,
                                                    ushort* __restrict__ xb) {
    int i = blockIdx.x * 256 + threadIdx.x;            // one float4 each
    if (i < N_NODES * D / 4) {
        float4 v = ((const float4*)xf)[i];
        ushort4 o;
        o.x = key1(f2b(v.x)); o.y = key1(f2b(v.y));
        o.z = key1(f2b(v.z)); o.w = key1(f2b(v.w));
        ((ushort4*)xb)[i] = o;
    }
}

// Wperm[lay][s][c][lane][j] = bf16(W[lay][32s + 8*(lane>>4) + j][16c + (lane&15)])
__global__ __launch_bounds__(256) void cvt_w_kernel(const float* __restrict__ Ws,
                                                    ushort* __restrict__ Wperm) {
    int i = blockIdx.x * 256 + threadIdx.x;
    if (i >= 3 * 4 * 4 * 64 * 8) return;
    int j    = i & 7;
    int lane = (i >> 3) & 63;
    int c    = (i >> 9) & 3;
    int s    = (i >> 11) & 3;
    int lay  = i >> 13;
    int k = 32 * s + 8 * (lane >> 4) + j;
    int d = 16 * c + (lane & 15);
    Wperm[i] = f2b(Ws[((size_t)lay * TWO_D + k) * D + d]);
}

// Generic drain path: 8/4/1-wide key-domain max over [j, end).
__device__ __forceinline__ void gather_tail(const u16x8* __restrict__ x8,
                                            const int* __restrict__ ssrc,
                                            int fl, int base, int j, int end,
                                            u16x8& m) {
    while (j < end) {
        const int cnt = min(end - j, 8);
        const int idx = ssrc[j + min(fl, cnt - 1)];
        int t = 0;
        if (cnt == 8) {
            int s0 = __shfl(idx, base,     64);
            int s1 = __shfl(idx, base + 1, 64);
            int s2 = __shfl(idx, base + 2, 64);
            int s3 = __shfl(idx, base + 3, 64);
            int s4 = __shfl(idx, base + 4, 64);
            int s5 = __shfl(idx, base + 5, 64);
            int s6 = __shfl(idx, base + 6, 64);
            int s7 = __shfl(idx, base + 7, 64);
            u16x8 r0 = x8[s0 * 8 + fl];
            u16x8 r1 = x8[s1 * 8 + fl];
            u16x8 r2 = x8[s2 * 8 + fl];
            u16x8 r3 = x8[s3 * 8 + fl];
            u16x8 r4 = x8[s4 * 8 + fl];
            u16x8 r5 = x8[s5 * 8 + fl];
            u16x8 r6 = x8[s6 * 8 + fl];
            u16x8 r7 = x8[s7 * 8 + fl];
            m = pkmax8(m, pkmax8(pkmax8(pkmax8(r0, r1), pkmax8(r2, r3)),
                                 pkmax8(pkmax8(r4, r5), pkmax8(r6, r7))));
            t = 8;
        }
        if (t + 4 <= cnt) {
            int s0 = __shfl(idx, base + t,     64);
            int s1 = __shfl(idx, base + t + 1, 64);
            int s2 = __shfl(idx, base + t + 2, 64);
            int s3 = __shfl(idx, base + t + 3, 64);
            u16x8 r0 = x8[s0 * 8 + fl];
            u16x8 r1 = x8[s1 * 8 + fl];
            u16x8 r2 = x8[s2 * 8 + fl];
            u16x8 r3 = x8[s3 * 8 + fl];
            m = pkmax8(m, pkmax8(pkmax8(r0, r1), pkmax8(r2, r3)));
            t += 4;
        }
        for (; t < cnt; ++t) {
            int s0 = __shfl(idx, base + t, 64);
            m = pkmax8(m, x8[s0 * 8 + fl]);
        }
        j += cnt;
    }
}

// ---------------------------------------------------------------------------
// Fused layer: 64 nodes per 256-thread block. Gather phase: each 8-lane group
// owns 2 nodes and software-pipelines them — the joint fast loop issues 16
// independent row loads (8 per node) before either reduction, doubling
// memory-level parallelism (the round-8 bottleneck). Key-domain pk-max.
// GEMM phase: wave per 16 nodes, 16 MFMA, bias+LN+ELU epilogue.
// ---------------------------------------------------------------------------
__global__ __launch_bounds__(256) void layer_kernel(
    const ushort* __restrict__ xb,      // keys
    const int* __restrict__ row_ptr,
    const int* __restrict__ deg,
    const int* __restrict__ ssrc,
    const ushort* __restrict__ Wperm,   // this layer's [4][4][64][8]
    const float* __restrict__ bias,
    const float* __restrict__ gamma,
    const float* __restrict__ beta,
    ushort* __restrict__ out_b,         // key out (layers 0,1) or nullptr
    float*  __restrict__ out_f)         // f32 out (layer 2) or nullptr
{
    __shared__ u16x8 xt[64][8];
    __shared__ u16x8 at[64][8];

    const int tid = threadIdx.x;
    const int fl = tid & 7;
    const int base = tid & 56;                 // 8-lane group base within wave
    const int grp = tid >> 3;                  // 0..31
    const u16x8* __restrict__ x8 = (const u16x8*)xb;
    const int nblk0 = blockIdx.x * 64;

    const int nlA = grp * 2, nlB = nlA + 1;
    const int nodeA = nblk0 + nlA, nodeB = nblk0 + nlB;
    const bool vA = nodeA < N_NODES, vB = nodeB < N_NODES;

    const u16x8 xsA = vA ? x8[nodeA * 8 + fl] : (u16x8)0;
    const u16x8 xsB = vB ? x8[nodeB * 8 + fl] : (u16x8)0;
    int jA = vA ? row_ptr[nodeA] : 0;
    int eA = vA ? jA + deg[nodeA] : 0;
    int jB = vB ? row_ptr[nodeB] : 0;
    int eB = vB ? jB + deg[nodeB] : 0;
    const bool hasA = eA > jA, hasB = eB > jB;

    u16x8 mA = (u16x8)0, mB = (u16x8)0;        // 0 < any legal key

    // Joint fast loop: 16 row loads in flight (8 per node).
    while (jA + 8 <= eA && jB + 8 <= eB) {
        const int idxA = ssrc[jA + fl];
        const int idxB = ssrc[jB + fl];
        int sA[8], sB[8];
#pragma unroll
        for (int t = 0; t < 8; ++t) sA[t] = __shfl(idxA, base + t, 64);
#pragma unroll
        for (int t = 0; t < 8; ++t) sB[t] = __shfl(idxB, base + t, 64);
        u16x8 rA[8], rB[8];
#pragma unroll
        for (int t = 0; t < 8; ++t) rA[t] = x8[sA[t] * 8 + fl];
#pragma unroll
        for (int t = 0; t < 8; ++t) rB[t] = x8[sB[t] * 8 + fl];
        mA = pkmax8(mA, pkmax8(pkmax8(pkmax8(rA[0], rA[1]), pkmax8(rA[2], rA[3])),
                               pkmax8(pkmax8(rA[4], rA[5]), pkmax8(rA[6], rA[7]))));
        mB = pkmax8(mB, pkmax8(pkmax8(pkmax8(rB[0], rB[1]), pkmax8(rB[2], rB[3])),
                               pkmax8(pkmax8(rB[4], rB[5]), pkmax8(rB[6], rB[7]))));
        jA += 8; jB += 8;
    }
    gather_tail(x8, ssrc, fl, base, jA, eA, mA);
    gather_tail(x8, ssrc, fl, base, jB, eB, mB);

    if (vA) {
        u16x8 xplain, o;
#pragma unroll
        for (int e = 0; e < 8; ++e) {
            const unsigned short xu = unkey1(xsA[e]);
            xplain[e] = xu;
            o[e] = hasA ? f2b(fmaxf(b2f(unkey1(mA[e])) - b2f(xu), 0.f))
                        : (unsigned short)0;
        }
        const int slot = fl ^ (nlA & 7);
        xt[nlA][slot] = xplain;
        at[nlA][slot] = o;
    }
    if (vB) {
        u16x8 xplain, o;
#pragma unroll
        for (int e = 0; e < 8; ++e) {
            const unsigned short xu = unkey1(xsB[e]);
            xplain[e] = xu;
            o[e] = hasB ? f2b(fmaxf(b2f(unkey1(mB[e])) - b2f(xu), 0.f))
                        : (unsigned short)0;
        }
        const int slot = fl ^ (nlB & 7);
        xt[nlB][slot] = xplain;
        at[nlB][slot] = o;
    }
    __syncthreads();

    // --- GEMM phase: wave per 16 nodes ---
    const int wave = tid >> 6;
    const int lane = tid & 63;
    const int n0 = nblk0 + wave * 16;
    if (n0 >= N_NODES) return;
    const int row = lane & 15;
    const int kb  = lane >> 4;
    const int nl  = wave * 16 + row;
    const int sw  = nl & 7;

    bf16x8 a0 = __builtin_bit_cast(bf16x8, xt[nl][kb ^ sw]);
    bf16x8 a1 = __builtin_bit_cast(bf16x8, xt[nl][(kb + 4) ^ sw]);
    bf16x8 a2 = __builtin_bit_cast(bf16x8, at[nl][kb ^ sw]);
    bf16x8 a3 = __builtin_bit_cast(bf16x8, at[nl][(kb + 4) ^ sw]);

    const bf16x8* __restrict__ wp = (const bf16x8*)Wperm;
    bf16x8 wf[4][4];
#pragma unroll
    for (int s = 0; s < 4; ++s)
#pragma unroll
        for (int c = 0; c < 4; ++c)
            wf[s][c] = wp[(s * 4 + c) * 64 + lane];

    f32x4 acc[4];
#pragma unroll
    for (int c = 0; c < 4; ++c) acc[c] = (f32x4){0.f, 0.f, 0.f, 0.f};
#pragma unroll
    for (int c = 0; c < 4; ++c) {
        acc[c] = __builtin_amdgcn_mfma_f32_16x16x32_bf16(a0, wf[0][c], acc[c], 0, 0, 0);
        acc[c] = __builtin_amdgcn_mfma_f32_16x16x32_bf16(a1, wf[1][c], acc[c], 0, 0, 0);
        acc[c] = __builtin_amdgcn_mfma_f32_16x16x32_bf16(a2, wf[2][c], acc[c], 0, 0, 0);
        acc[c] = __builtin_amdgcn_mfma_f32_16x16x32_bf16(a3, wf[3][c], acc[c], 0, 0, 0);
    }

    float bv[4], gv[4], btv[4];
#pragma unroll
    for (int c = 0; c < 4; ++c) {
        const int col = 16 * c + row;
        bv[c] = bias[col]; gv[c] = gamma[col]; btv[c] = beta[col];
    }

#pragma unroll
    for (int j = 0; j < 4; ++j) {
        float h0 = acc[0][j] + bv[0];
        float h1 = acc[1][j] + bv[1];
        float h2 = acc[2][j] + bv[2];
        float h3 = acc[3][j] + bv[3];
        float ps = (h0 + h1) + (h2 + h3);
        ps += __shfl_xor(ps, 1, 64);
        ps += __shfl_xor(ps, 2, 64);
        ps += __shfl_xor(ps, 4, 64);
        ps += __shfl_xor(ps, 8, 64);
        const float mu = ps * (1.0f / 64.0f);
        const float d0 = h0 - mu, d1 = h1 - mu, d2 = h2 - mu, d3 = h3 - mu;
        float vs = (d0 * d0 + d1 * d1) + (d2 * d2 + d3 * d3);
        vs += __shfl_xor(vs, 1, 64);
        vs += __shfl_xor(vs, 2, 64);
        vs += __shfl_xor(vs, 4, 64);
        vs += __shfl_xor(vs, 8, 64);
        const float rstd = rsqrtf(vs * (1.0f / 64.0f) + LN_EPS);

        const int node = n0 + 4 * kb + j;
        const float dd[4] = {d0, d1, d2, d3};
#pragma unroll
        for (int c = 0; c < 4; ++c) {
            float o = dd[c] * rstd * gv[c] + btv[c];
            o = o > 0.f ? o : expm1f(o);
            if (out_f) out_f[node * D + 16 * c + row] = o;
            else       out_b[node * D + 16 * c + row] = key1(f2b(o));
        }
    }
}

static inline size_t alignup(size_t v) { return (v + 255) & ~(size_t)255; }

extern "C" void kernel_launch(void* const* d_in, const int* in_sizes, int n_in,
                              void* d_out, int out_size, void* d_ws, size_t ws_size,
                              hipStream_t stream) {
    const float* features = (const float*)d_in[0];
    const int*   src      = (const int*)d_in[1];
    const int*   dst      = (const int*)d_in[2];
    const float* Ws       = (const float*)d_in[3];
    const float* bs       = (const float*)d_in[4];
    const float* gammas   = (const float*)d_in[5];
    const float* betas    = (const float*)d_in[6];
    float* out = (float*)d_out;

    char* ws = (char*)d_ws;
    size_t off = 0;
    int* row_ptr = (int*)(ws + off); off = alignup(off + sizeof(int) * N_NODES);
    int* deg     = (int*)(ws + off); off = alignup(off + sizeof(int) * N_NODES);
    int* bofs    = (int*)(ws + off); off = alignup(off + sizeof(int) * (size_t)NEB * BOFS_STRIDE);
    int* ebuf    = (int*)(ws + off); off = alignup(off + sizeof(int) * (size_t)NEB * EPB);
    int* ssrc    = (int*)(ws + off); off = alignup(off + sizeof(int) * (size_t)NBUCK * BCAP);
    ushort* xbA  = (ushort*)(ws + off); off = alignup(off + sizeof(ushort) * (size_t)N_NODES * D);
    ushort* xbB  = (ushort*)(ws + off); off = alignup(off + sizeof(ushort) * (size_t)N_NODES * D);
    ushort* Wperm= (ushort*)(ws + off); off = alignup(off + sizeof(ushort) * 3 * TWO_D * D);

    // --- build padded CSR (LDS-sorted chunks -> per-bucket merge, once) ---
    bscat_kernel<<<NEB, 1024, 0, stream>>>(src, dst, ebuf, bofs);
    bbuild_kernel<<<NBUCK, 512, 0, stream>>>(ebuf, bofs, row_ptr, deg, ssrc);

    // --- converters ---
    cvt_x_kernel<<<(N_NODES * D / 4 + 255) / 256, 256, 0, stream>>>(features, xbA);
    cvt_w_kernel<<<(3 * 4 * 4 * 64 * 8 + 255) / 256, 256, 0, stream>>>(Ws, Wperm);

    // --- 3 fused layers ---
    const int l_blocks = (N_NODES + 63) / 64;          // 1563

    ushort* xin = xbA;
    ushort* xnb[3] = { xbB, xbA, nullptr };
    for (int l = 0; l < 3; ++l) {
        layer_kernel<<<l_blocks, 256, 0, stream>>>(
            xin, row_ptr, deg, ssrc,
            Wperm + (size_t)l * 16 * 64 * 8,
            bs + (size_t)l * D,
            gammas + (size_t)l * D,
            betas + (size_t)l * D,
            xnb[l],
            (l == 2) ? out : nullptr);
        xin = xnb[l];
    }
}

// Round 10
// 187.179 us; speedup vs baseline: 1.2093x; 1.2093x over previous
//
#include <hip/hip_runtime.h>
#include <hip/hip_bf16.h>
#include <math.h>

#define N_NODES 100000
#define N_EDGES 1600000
#define D 64
#define TWO_D 128
#define LN_EPS 1e-5f

#define BSHIFT 7                                   // 128 nodes per bucket
#define BMASK 127
#define NBUCK ((N_NODES + 127) >> BSHIFT)          // 782
#define BCAP 4096                                  // per-bucket CSR capacity (mean 2046, +45 sigma)
#define EPB 8192                                   // edges per bscat block
#define NEB ((N_EDGES + EPB - 1) / EPB)            // 196
#define BOFS_STRIDE (NBUCK + 1)
#define NTILES ((N_NODES + 63) / 64)               // 1563

typedef __attribute__((ext_vector_type(4))) float f32x4;
typedef __attribute__((ext_vector_type(8))) short bf16x8;
typedef __attribute__((ext_vector_type(8))) unsigned short u16x8;

__device__ __forceinline__ float b2f(unsigned short u) {
    return __uint_as_float(((unsigned)u) << 16);
}
__device__ __forceinline__ unsigned short f2b(float f) {
    __hip_bfloat16 h = __float2bfloat16(f);   // RNE
    return __builtin_bit_cast(unsigned short, h);
}
// Order-preserving bf16 <-> u16 key (unsigned compare == float compare).
__device__ __forceinline__ unsigned short key1(unsigned short u) {
    return (u & 0x8000) ? (unsigned short)~u : (unsigned short)(u ^ 0x8000);
}
__device__ __forceinline__ unsigned short unkey1(unsigned short k) {
    return (k & 0x8000) ? (unsigned short)(k ^ 0x8000) : (unsigned short)~k;
}
__device__ __forceinline__ u16x8 pkmax8(u16x8 a, u16x8 b) {
    return __builtin_elementwise_max(a, b);       // v_pk_max_u16 x4
}

// ---------------------------------------------------------------------------
// bscat: per-block FULL LDS sort by bucket; coalesced global writes; no
// global atomics. Emits sorted chunk + per-(block,bucket) exclusive offsets.
// Edge record packed to int32: (src << 7) | (dst & 127); src < 2^17.
// ---------------------------------------------------------------------------
__global__ __launch_bounds__(1024) void bscat_kernel(const int* __restrict__ src,
                                                     const int* __restrict__ dst,
                                                     int* __restrict__ ebuf,
                                                     int* __restrict__ bofs) {
    __shared__ int cnt[NBUCK];
    __shared__ int off[NBUCK];
    __shared__ int stage[EPB];
    const int e0 = blockIdx.x * EPB;
    const int nE = min(EPB, N_EDGES - e0);
    int d[8], s[8];

    for (int i = threadIdx.x; i < NBUCK; i += 1024) cnt[i] = 0;
    __syncthreads();
#pragma unroll
    for (int k = 0; k < 8; ++k) {
        const int i = threadIdx.x + k * 1024;
        if (i < nE) {
            d[k] = dst[e0 + i];
            s[k] = src[e0 + i];
            atomicAdd(&cnt[d[k] >> BSHIFT], 1);
        }
    }
    __syncthreads();
    // Hillis-Steele inclusive scan over NBUCK (<1024)
    const int v = (threadIdx.x < NBUCK) ? cnt[threadIdx.x] : 0;
    if (threadIdx.x < NBUCK) off[threadIdx.x] = v;
    __syncthreads();
    for (int o = 1; o < 1024; o <<= 1) {
        int t = 0;
        if (threadIdx.x < NBUCK && threadIdx.x >= o) t = off[threadIdx.x - o];
        __syncthreads();
        if (threadIdx.x < NBUCK) off[threadIdx.x] += t;
        __syncthreads();
    }
    if (threadIdx.x < NBUCK) {
        const int ex = off[threadIdx.x] - v;      // exclusive
        bofs[blockIdx.x * BOFS_STRIDE + threadIdx.x] = ex;
        off[threadIdx.x] = ex;
        cnt[threadIdx.x] = 0;
    }
    if (threadIdx.x == 0) bofs[blockIdx.x * BOFS_STRIDE + NBUCK] = nE;
    __syncthreads();
#pragma unroll
    for (int k = 0; k < 8; ++k) {
        const int i = threadIdx.x + k * 1024;
        if (i < nE) {
            const int b = d[k] >> BSHIFT;
            const int r = atomicAdd(&cnt[b], 1);
            stage[off[b] + r] = (s[k] << BSHIFT) | (d[k] & BMASK);
        }
    }
    __syncthreads();
    for (int i = threadIdx.x; i < nE; i += 1024)
        ebuf[e0 + i] = stage[i];
}

// ---------------------------------------------------------------------------
// bbuild: one block per bucket. Gathers the bucket's runs from all 196 sorted
// chunks into LDS, counting-sorts by node-within-bucket, emits padded CSR.
// ---------------------------------------------------------------------------
__global__ __launch_bounds__(512) void bbuild_kernel(const int* __restrict__ ebuf,
                                                     const int* __restrict__ bofs,
                                                     int* __restrict__ row_ptr,
                                                     int* __restrict__ deg,
                                                     int* __restrict__ ssrc) {
    __shared__ int rst[NEB], rlen[NEB], rdst[NEB];
    __shared__ int stage[BCAP];
    __shared__ int stage2[BCAP];
    __shared__ int cnt[128], excl[128];
    const int b = blockIdx.x;
    const int nb0 = b << BSHIFT;

    for (int i = threadIdx.x; i < NEB; i += 512) {
        const int st = bofs[i * BOFS_STRIDE + b];
        const int en = bofs[i * BOFS_STRIDE + b + 1];
        rst[i] = st; rlen[i] = en - st;
    }
    __syncthreads();
    // scan rlen -> rdst (inclusive), NEB=196 < 256
    const int rv = (threadIdx.x < NEB) ? rlen[threadIdx.x] : 0;
    if (threadIdx.x < NEB) rdst[threadIdx.x] = rv;
    __syncthreads();
    for (int o = 1; o < 256; o <<= 1) {
        int t = 0;
        if (threadIdx.x < NEB && threadIdx.x >= o) t = rdst[threadIdx.x - o];
        __syncthreads();
        if (threadIdx.x < NEB) rdst[threadIdx.x] += t;
        __syncthreads();
    }
    const int total = rdst[NEB - 1];

    // gather runs: wave w handles regions w, w+8, ...
    const int wave = threadIdx.x >> 6, lane = threadIdx.x & 63;
    for (int i = wave; i < NEB; i += 8) {
        const int st = rst[i], len = rlen[i], doff = rdst[i] - len;
        for (int l = lane; l < len; l += 64)
            stage[doff + l] = ebuf[i * EPB + st + l];
    }
    if (threadIdx.x < 128) cnt[threadIdx.x] = 0;
    __syncthreads();

    // counting sort by node-within-bucket
    for (int i = threadIdx.x; i < total; i += 512)
        atomicAdd(&cnt[stage[i] & BMASK], 1);
    __syncthreads();
    const int cv = (threadIdx.x < 128) ? cnt[threadIdx.x] : 0;
    if (threadIdx.x < 128) excl[threadIdx.x] = cv;
    __syncthreads();
    for (int o = 1; o < 128; o <<= 1) {
        int t = 0;
        if (threadIdx.x < 128 && threadIdx.x >= o) t = excl[threadIdx.x - o];
        __syncthreads();
        if (threadIdx.x < 128) excl[threadIdx.x] += t;
        __syncthreads();
    }
    if (threadIdx.x < 128) {
        excl[threadIdx.x] -= cv;              // exclusive
        const int node = nb0 + threadIdx.x;
        if (node < N_NODES) {
            row_ptr[node] = b * BCAP + excl[threadIdx.x];
            deg[node] = cv;
        }
        cnt[threadIdx.x] = 0;
    }
    __syncthreads();
    for (int i = threadIdx.x; i < total; i += 512) {
        const int p = stage[i];
        const int dl = p & BMASK;
        const int r = atomicAdd(&cnt[dl], 1);
        stage2[excl[dl] + r] = p >> BSHIFT;
    }
    __syncthreads();
    for (int i = threadIdx.x; i < total; i += 512)
        ssrc[b * BCAP + i] = stage2[i];
}

// ---------------------------------------------------------------------------
// dbal: per 64-node tile, bitonic-sort node-local ids by degree (ascending)
// and pair rank g with rank 63-g -> every gather group gets ~equal work.
// One wave per tile, 4 tiles per block.
// ---------------------------------------------------------------------------
__global__ __launch_bounds__(256) void dbal_kernel(const int* __restrict__ deg,
                                                   ushort* __restrict__ pairs) {
    const int tile = blockIdx.x * 4 + (threadIdx.x >> 6);
    const int lane = threadIdx.x & 63;
    if (tile >= NTILES) return;
    const int node = tile * 64 + lane;
    const int d = (node < N_NODES) ? deg[node] : 0;
    int key = (d << 6) | lane;
#pragma unroll
    for (int k = 2; k <= 64; k <<= 1) {
#pragma unroll
        for (int j = k >> 1; j > 0; j >>= 1) {
            const int other = __shfl_xor(key, j, 64);
            const bool up = ((lane & k) == 0);      // k=64: always ascending
            const bool lower = ((lane & j) == 0);
            key = (lower == up) ? min(key, other) : max(key, other);
        }
    }
    const int small_nl = key & 63;
    const int big_nl = __shfl(key, 63 - lane, 64) & 63;
    if (lane < 32)
        pairs[tile * 32 + lane] = (ushort)((big_nl << 6) | small_nl);
}

// ---------------------------------------------------------------------------
// Converters. x is stored as order-preserving u16 KEYS.
// ---------------------------------------------------------------------------
__global__ __launch_bounds__(256) void cvt_x_kernel(const float* __restrict__ xf,
                                                    ushort* __restrict__ xb) {
    int i = blockIdx.x * 256 + threadIdx.x;            // one float4 each
    if (i < N_NODES * D / 4) {
        float4 v = ((const float4*)xf)[i];
        ushort4 o;
        o.x = key1(f2b(v.x)); o.y = key1(f2b(v.y));
        o.z = key1(f2b(v.z)); o.w = key1(f2b(v.w));
        ((ushort4*)xb)[i] = o;
    }
}

// Wperm[lay][s][c][lane][j] = bf16(W[lay][32s + 8*(lane>>4) + j][16c + (lane&15)])
__global__ __launch_bounds__(256) void cvt_w_kernel(const float* __restrict__ Ws,
                                                    ushort* __restrict__ Wperm) {
    int i = blockIdx.x * 256 + threadIdx.x;
    if (i >= 3 * 4 * 4 * 64 * 8) return;
    int j    = i & 7;
    int lane = (i >> 3) & 63;
    int c    = (i >> 9) & 3;
    int s    = (i >> 11) & 3;
    int lay  = i >> 13;
    int k = 32 * s + 8 * (lane >> 4) + j;
    int d = 16 * c + (lane & 15);
    Wperm[i] = f2b(Ws[((size_t)lay * TWO_D + k) * D + d]);
}

// 8/4/1-wide key-domain max over [j, end).
__device__ __forceinline__ void gather_range(const u16x8* __restrict__ x8,
                                             const int* __restrict__ ssrc,
                                             int fl, int base, int j, int end,
                                             u16x8& m) {
    while (j < end) {
        const int cnt = min(end - j, 8);
        const int idx = ssrc[j + min(fl, cnt - 1)];
        int t = 0;
        if (cnt == 8) {
            int s0 = __shfl(idx, base,     64);
            int s1 = __shfl(idx, base + 1, 64);
            int s2 = __shfl(idx, base + 2, 64);
            int s3 = __shfl(idx, base + 3, 64);
            int s4 = __shfl(idx, base + 4, 64);
            int s5 = __shfl(idx, base + 5, 64);
            int s6 = __shfl(idx, base + 6, 64);
            int s7 = __shfl(idx, base + 7, 64);
            u16x8 r0 = x8[s0 * 8 + fl];
            u16x8 r1 = x8[s1 * 8 + fl];
            u16x8 r2 = x8[s2 * 8 + fl];
            u16x8 r3 = x8[s3 * 8 + fl];
            u16x8 r4 = x8[s4 * 8 + fl];
            u16x8 r5 = x8[s5 * 8 + fl];
            u16x8 r6 = x8[s6 * 8 + fl];
            u16x8 r7 = x8[s7 * 8 + fl];
            m = pkmax8(m, pkmax8(pkmax8(pkmax8(r0, r1), pkmax8(r2, r3)),
                                 pkmax8(pkmax8(r4, r5), pkmax8(r6, r7))));
            t = 8;
        }
        if (t + 4 <= cnt) {
            int s0 = __shfl(idx, base + t,     64);
            int s1 = __shfl(idx, base + t + 1, 64);
            int s2 = __shfl(idx, base + t + 2, 64);
            int s3 = __shfl(idx, base + t + 3, 64);
            u16x8 r0 = x8[s0 * 8 + fl];
            u16x8 r1 = x8[s1 * 8 + fl];
            u16x8 r2 = x8[s2 * 8 + fl];
            u16x8 r3 = x8[s3 * 8 + fl];
            m = pkmax8(m, pkmax8(pkmax8(r0, r1), pkmax8(r2, r3)));
            t += 4;
        }
        for (; t < cnt; ++t) {
            int s0 = __shfl(idx, base + t, 64);
            m = pkmax8(m, x8[s0 * 8 + fl]);
        }
        j += cnt;
    }
}

// ---------------------------------------------------------------------------
// Fused layer: 64 nodes per 256-thread block. Each 8-lane group gathers a
// degree-balanced PAIR of node-local ids (from dbal) serially — block gather
// time ≈ 2x mean degree instead of max-over-groups. Key-domain pk-max.
// GEMM phase: wave per 16 nodes, 16 MFMA, bias+LN+ELU epilogue.
// ---------------------------------------------------------------------------
__global__ __launch_bounds__(256) void layer_kernel(
    const ushort* __restrict__ xb,      // keys
    const int* __restrict__ row_ptr,
    const int* __restrict__ deg,
    const int* __restrict__ ssrc,
    const ushort* __restrict__ pairs,
    const ushort* __restrict__ Wperm,   // this layer's [4][4][64][8]
    const float* __restrict__ bias,
    const float* __restrict__ gamma,
    const float* __restrict__ beta,
    ushort* __restrict__ out_b,         // key out (layers 0,1) or nullptr
    float*  __restrict__ out_f)         // f32 out (layer 2) or nullptr
{
    __shared__ u16x8 xt[64][8];
    __shared__ u16x8 at[64][8];

    const int tid = threadIdx.x;
    const int fl = tid & 7;
    const int base = tid & 56;                 // 8-lane group base within wave
    const int grp = tid >> 3;                  // 0..31
    const u16x8* __restrict__ x8 = (const u16x8*)xb;
    const int nblk0 = blockIdx.x * 64;

    const int pr = pairs[blockIdx.x * 32 + grp];
    const int nls[2] = { pr & 63, (pr >> 6) & 63 };

#pragma unroll
    for (int q = 0; q < 2; ++q) {
        const int nl = nls[q];
        const int node = nblk0 + nl;
        if (node < N_NODES) {
            const u16x8 xs = x8[node * 8 + fl];
            const int beg = row_ptr[node];
            const int end = beg + deg[node];

            u16x8 m = (u16x8)0;                // 0 < min legal key
            gather_range(x8, ssrc, fl, base, beg, end, m);

            u16x8 xplain, o;
            const bool has = (end > beg);
#pragma unroll
            for (int e = 0; e < 8; ++e) {
                const unsigned short xu = unkey1(xs[e]);
                xplain[e] = xu;
                o[e] = has ? f2b(fmaxf(b2f(unkey1(m[e])) - b2f(xu), 0.f))
                           : (unsigned short)0;
            }
            const int slot = fl ^ (nl & 7);
            xt[nl][slot] = xplain;
            at[nl][slot] = o;
        }
    }
    __syncthreads();

    // --- GEMM phase: wave per 16 nodes ---
    const int wave = tid >> 6;
    const int lane = tid & 63;
    const int n0 = nblk0 + wave * 16;
    if (n0 >= N_NODES) return;
    const int row = lane & 15;
    const int kb  = lane >> 4;
    const int nl  = wave * 16 + row;
    const int sw  = nl & 7;

    bf16x8 a0 = __builtin_bit_cast(bf16x8, xt[nl][kb ^ sw]);
    bf16x8 a1 = __builtin_bit_cast(bf16x8, xt[nl][(kb + 4) ^ sw]);
    bf16x8 a2 = __builtin_bit_cast(bf16x8, at[nl][kb ^ sw]);
    bf16x8 a3 = __builtin_bit_cast(bf16x8, at[nl][(kb + 4) ^ sw]);

    const bf16x8* __restrict__ wp = (const bf16x8*)Wperm;
    bf16x8 wf[4][4];
#pragma unroll
    for (int s = 0; s < 4; ++s)
#pragma unroll
        for (int c = 0; c < 4; ++c)
            wf[s][c] = wp[(s * 4 + c) * 64 + lane];

    f32x4 acc[4];
#pragma unroll
    for (int c = 0; c < 4; ++c) acc[c] = (f32x4){0.f, 0.f, 0.f, 0.f};
#pragma unroll
    for (int c = 0; c < 4; ++c) {
        acc[c] = __builtin_amdgcn_mfma_f32_16x16x32_bf16(a0, wf[0][c], acc[c], 0, 0, 0);
        acc[c] = __builtin_amdgcn_mfma_f32_16x16x32_bf16(a1, wf[1][c], acc[c], 0, 0, 0);
        acc[c] = __builtin_amdgcn_mfma_f32_16x16x32_bf16(a2, wf[2][c], acc[c], 0, 0, 0);
        acc[c] = __builtin_amdgcn_mfma_f32_16x16x32_bf16(a3, wf[3][c], acc[c], 0, 0, 0);
    }

    float bv[4], gv[4], btv[4];
#pragma unroll
    for (int c = 0; c < 4; ++c) {
        const int col = 16 * c + row;
        bv[c] = bias[col]; gv[c] = gamma[col]; btv[c] = beta[col];
    }

#pragma unroll
    for (int j = 0; j < 4; ++j) {
        float h0 = acc[0][j] + bv[0];
        float h1 = acc[1][j] + bv[1];
        float h2 = acc[2][j] + bv[2];
        float h3 = acc[3][j] + bv[3];
        float ps = (h0 + h1) + (h2 + h3);
        ps += __shfl_xor(ps, 1, 64);
        ps += __shfl_xor(ps, 2, 64);
        ps += __shfl_xor(ps, 4, 64);
        ps += __shfl_xor(ps, 8, 64);
        const float mu = ps * (1.0f / 64.0f);
        const float d0 = h0 - mu, d1 = h1 - mu, d2 = h2 - mu, d3 = h3 - mu;
        float vs = (d0 * d0 + d1 * d1) + (d2 * d2 + d3 * d3);
        vs += __shfl_xor(vs, 1, 64);
        vs += __shfl_xor(vs, 2, 64);
        vs += __shfl_xor(vs, 4, 64);
        vs += __shfl_xor(vs, 8, 64);
        const float rstd = rsqrtf(vs * (1.0f / 64.0f) + LN_EPS);

        const int node = n0 + 4 * kb + j;
        const float dd[4] = {d0, d1, d2, d3};
#pragma unroll
        for (int c = 0; c < 4; ++c) {
            float o = dd[c] * rstd * gv[c] + btv[c];
            o = o > 0.f ? o : expm1f(o);
            if (out_f) out_f[node * D + 16 * c + row] = o;
            else       out_b[node * D + 16 * c + row] = key1(f2b(o));
        }
    }
}

static inline size_t alignup(size_t v) { return (v + 255) & ~(size_t)255; }

extern "C" void kernel_launch(void* const* d_in, const int* in_sizes, int n_in,
                              void* d_out, int out_size, void* d_ws, size_t ws_size,
                              hipStream_t stream) {
    const float* features = (const float*)d_in[0];
    const int*   src      = (const int*)d_in[1];
    const int*   dst      = (const int*)d_in[2];
    const float* Ws       = (const float*)d_in[3];
    const float* bs       = (const float*)d_in[4];
    const float* gammas   = (const float*)d_in[5];
    const float* betas    = (const float*)d_in[6];
    float* out = (float*)d_out;

    char* ws = (char*)d_ws;
    size_t off = 0;
    int* row_ptr = (int*)(ws + off); off = alignup(off + sizeof(int) * N_NODES);
    int* deg     = (int*)(ws + off); off = alignup(off + sizeof(int) * N_NODES);
    int* bofs    = (int*)(ws + off); off = alignup(off + sizeof(int) * (size_t)NEB * BOFS_STRIDE);
    int* ebuf    = (int*)(ws + off); off = alignup(off + sizeof(int) * (size_t)NEB * EPB);
    int* ssrc    = (int*)(ws + off); off = alignup(off + sizeof(int) * (size_t)NBUCK * BCAP);
    ushort* prs  = (ushort*)(ws + off); off = alignup(off + sizeof(ushort) * (size_t)NTILES * 32);
    ushort* xbA  = (ushort*)(ws + off); off = alignup(off + sizeof(ushort) * (size_t)N_NODES * D);
    ushort* xbB  = (ushort*)(ws + off); off = alignup(off + sizeof(ushort) * (size_t)N_NODES * D);
    ushort* Wperm= (ushort*)(ws + off); off = alignup(off + sizeof(ushort) * 3 * TWO_D * D);

    // --- build padded CSR (LDS-sorted chunks -> per-bucket merge, once) ---
    bscat_kernel<<<NEB, 1024, 0, stream>>>(src, dst, ebuf, bofs);
    bbuild_kernel<<<NBUCK, 512, 0, stream>>>(ebuf, bofs, row_ptr, deg, ssrc);
    dbal_kernel<<<(NTILES + 3) / 4, 256, 0, stream>>>(deg, prs);

    // --- converters ---
    cvt_x_kernel<<<(N_NODES * D / 4 + 255) / 256, 256, 0, stream>>>(features, xbA);
    cvt_w_kernel<<<(3 * 4 * 4 * 64 * 8 + 255) / 256, 256, 0, stream>>>(Ws, Wperm);

    // --- 3 fused layers ---
    ushort* xin = xbA;
    ushort* xnb[3] = { xbB, xbA, nullptr };
    for (int l = 0; l < 3; ++l) {
        layer_kernel<<<NTILES, 256, 0, stream>>>(
            xin, row_ptr, deg, ssrc, prs,
            Wperm + (size_t)l * 16 * 64 * 8,
            bs + (size_t)l * D,
            gammas + (size_t)l * D,
            betas + (size_t)l * D,
            xnb[l],
            (l == 2) ? out : nullptr);
        xin = xnb[l];
    }
}

// Round 11
// 178.990 us; speedup vs baseline: 1.2647x; 1.0457x over previous
//
#include <hip/hip_runtime.h>
#include <hip/hip_bf16.h>
#include <math.h>

#define N_NODES 100000
#define N_EDGES 1600000
#define D 64
#define TWO_D 128
#define LN_EPS 1e-5f

#define BSHIFT 7                                   // 128 nodes per bucket
#define BMASK 127
#define NBUCK ((N_NODES + 127) >> BSHIFT)          // 782
#define BCAP 4096                                  // per-bucket CSR capacity (mean 2046, +45 sigma)
#define EPB 8192                                   // edges per bscat block
#define NEB ((N_EDGES + EPB - 1) / EPB)            // 196
#define BOFS_STRIDE (NBUCK + 1)
#define NTILES ((N_NODES + 63) / 64)               // 1563
#define XQ (N_NODES * D / 4)                       // float4 count for x cvt
#define WELEMS (3 * 4 * 4 * 64 * 8)                // Wperm element count

typedef __attribute__((ext_vector_type(4))) float f32x4;
typedef __attribute__((ext_vector_type(8))) _Float16 h16x8;
typedef __attribute__((ext_vector_type(8))) unsigned short u16x8;

__device__ __forceinline__ unsigned short f2h(float f) {
    return __builtin_bit_cast(unsigned short, (_Float16)f);   // RNE
}
// fp16 packed max on u16 storage (v_pk_max_f16; data is NaN-free).
__device__ __forceinline__ u16x8 pkmaxh(u16x8 a, u16x8 b) {
    return __builtin_bit_cast(u16x8,
        __builtin_elementwise_max(__builtin_bit_cast(h16x8, a),
                                  __builtin_bit_cast(h16x8, b)));
}

// ---------------------------------------------------------------------------
// bscat: per-block FULL LDS sort by bucket; coalesced global writes; no
// global atomics. Emits sorted chunk + per-(block,bucket) exclusive offsets.
// Edge record packed to int32: (src << 7) | (dst & 127); src < 2^17.
// ---------------------------------------------------------------------------
__global__ __launch_bounds__(1024) void bscat_kernel(const int* __restrict__ src,
                                                     const int* __restrict__ dst,
                                                     int* __restrict__ ebuf,
                                                     int* __restrict__ bofs) {
    __shared__ int cnt[NBUCK];
    __shared__ int off[NBUCK];
    __shared__ int stage[EPB];
    const int e0 = blockIdx.x * EPB;
    const int nE = min(EPB, N_EDGES - e0);
    int d[8], s[8];

    for (int i = threadIdx.x; i < NBUCK; i += 1024) cnt[i] = 0;
    __syncthreads();
#pragma unroll
    for (int k = 0; k < 8; ++k) {
        const int i = threadIdx.x + k * 1024;
        if (i < nE) {
            d[k] = dst[e0 + i];
            s[k] = src[e0 + i];
            atomicAdd(&cnt[d[k] >> BSHIFT], 1);
        }
    }
    __syncthreads();
    // Hillis-Steele inclusive scan over NBUCK (<1024)
    const int v = (threadIdx.x < NBUCK) ? cnt[threadIdx.x] : 0;
    if (threadIdx.x < NBUCK) off[threadIdx.x] = v;
    __syncthreads();
    for (int o = 1; o < 1024; o <<= 1) {
        int t = 0;
        if (threadIdx.x < NBUCK && threadIdx.x >= o) t = off[threadIdx.x - o];
        __syncthreads();
        if (threadIdx.x < NBUCK) off[threadIdx.x] += t;
        __syncthreads();
    }
    if (threadIdx.x < NBUCK) {
        const int ex = off[threadIdx.x] - v;      // exclusive
        bofs[blockIdx.x * BOFS_STRIDE + threadIdx.x] = ex;
        off[threadIdx.x] = ex;
        cnt[threadIdx.x] = 0;
    }
    if (threadIdx.x == 0) bofs[blockIdx.x * BOFS_STRIDE + NBUCK] = nE;
    __syncthreads();
#pragma unroll
    for (int k = 0; k < 8; ++k) {
        const int i = threadIdx.x + k * 1024;
        if (i < nE) {
            const int b = d[k] >> BSHIFT;
            const int r = atomicAdd(&cnt[b], 1);
            stage[off[b] + r] = (s[k] << BSHIFT) | (d[k] & BMASK);
        }
    }
    __syncthreads();
    for (int i = threadIdx.x; i < nE; i += 1024)
        ebuf[e0 + i] = stage[i];
}

// ---------------------------------------------------------------------------
// bbuild: one block per bucket. Gathers the bucket's runs from all 196 sorted
// chunks into LDS, counting-sorts by node-within-bucket, emits padded CSR,
// and (fused) computes degree-balanced pairs for its two 64-node tiles.
// ---------------------------------------------------------------------------
__global__ __launch_bounds__(512) void bbuild_kernel(const int* __restrict__ ebuf,
                                                     const int* __restrict__ bofs,
                                                     int* __restrict__ row_ptr,
                                                     int* __restrict__ deg,
                                                     int* __restrict__ ssrc,
                                                     ushort* __restrict__ pairs) {
    __shared__ int rst[NEB], rlen[NEB], rdst[NEB];
    __shared__ int stage[BCAP];
    __shared__ int stage2[BCAP];
    __shared__ int cnt[128], excl[128];
    const int b = blockIdx.x;
    const int nb0 = b << BSHIFT;

    for (int i = threadIdx.x; i < NEB; i += 512) {
        const int st = bofs[i * BOFS_STRIDE + b];
        const int en = bofs[i * BOFS_STRIDE + b + 1];
        rst[i] = st; rlen[i] = en - st;
    }
    __syncthreads();
    // scan rlen -> rdst (inclusive), NEB=196 < 256
    const int rv = (threadIdx.x < NEB) ? rlen[threadIdx.x] : 0;
    if (threadIdx.x < NEB) rdst[threadIdx.x] = rv;
    __syncthreads();
    for (int o = 1; o < 256; o <<= 1) {
        int t = 0;
        if (threadIdx.x < NEB && threadIdx.x >= o) t = rdst[threadIdx.x - o];
        __syncthreads();
        if (threadIdx.x < NEB) rdst[threadIdx.x] += t;
        __syncthreads();
    }
    const int total = rdst[NEB - 1];

    // gather runs: wave w handles regions w, w+8, ...
    const int wave = threadIdx.x >> 6, lane = threadIdx.x & 63;
    for (int i = wave; i < NEB; i += 8) {
        const int st = rst[i], len = rlen[i], doff = rdst[i] - len;
        for (int l = lane; l < len; l += 64)
            stage[doff + l] = ebuf[i * EPB + st + l];
    }
    if (threadIdx.x < 128) cnt[threadIdx.x] = 0;
    __syncthreads();

    // counting sort by node-within-bucket
    for (int i = threadIdx.x; i < total; i += 512)
        atomicAdd(&cnt[stage[i] & BMASK], 1);
    __syncthreads();
    const int cv = (threadIdx.x < 128) ? cnt[threadIdx.x] : 0;
    if (threadIdx.x < 128) excl[threadIdx.x] = cv;
    __syncthreads();
    for (int o = 1; o < 128; o <<= 1) {
        int t = 0;
        if (threadIdx.x < 128 && threadIdx.x >= o) t = excl[threadIdx.x - o];
        __syncthreads();
        if (threadIdx.x < 128) excl[threadIdx.x] += t;
        __syncthreads();
    }
    if (threadIdx.x < 128) {
        excl[threadIdx.x] -= cv;              // exclusive
        const int node = nb0 + threadIdx.x;
        if (node < N_NODES) {
            row_ptr[node] = b * BCAP + excl[threadIdx.x];
            deg[node] = cv;
        }
        cnt[threadIdx.x] = 0;
    }

    // fused dbal: bitonic-sort each 64-node tile by degree, pair g <-> 63-g.
    if (threadIdx.x < 128) {
        const int tile = 2 * b + (threadIdx.x >> 6);
        if (tile < NTILES) {
            int key = (cv << 6) | lane;
#pragma unroll
            for (int k = 2; k <= 64; k <<= 1) {
#pragma unroll
                for (int jj = k >> 1; jj > 0; jj >>= 1) {
                    const int other = __shfl_xor(key, jj, 64);
                    const bool up = ((lane & k) == 0);
                    const bool lower = ((lane & jj) == 0);
                    key = (lower == up) ? min(key, other) : max(key, other);
                }
            }
            const int small_nl = key & 63;
            const int big_nl = __shfl(key, 63 - lane, 64) & 63;
            if (lane < 32)
                pairs[tile * 32 + lane] = (ushort)((big_nl << 6) | small_nl);
        }
    }
    __syncthreads();

    for (int i = threadIdx.x; i < total; i += 512) {
        const int p = stage[i];
        const int dl = p & BMASK;
        const int r = atomicAdd(&cnt[dl], 1);
        stage2[excl[dl] + r] = p >> BSHIFT;
    }
    __syncthreads();
    for (int i = threadIdx.x; i < total; i += 512)
        ssrc[b * BCAP + i] = stage2[i];
}

// ---------------------------------------------------------------------------
// Fused converter: x (f32 -> fp16) and Wperm (f32 -> fp16, MFMA fragment
// order: Wperm[lay][s][c][lane][j] = W[lay][32s + 8*(lane>>4) + j][16c + (lane&15)])
// ---------------------------------------------------------------------------
__global__ __launch_bounds__(256) void cvt_kernel(const float* __restrict__ xf,
                                                  const float* __restrict__ Ws,
                                                  ushort* __restrict__ xb,
                                                  ushort* __restrict__ Wperm) {
    int i = blockIdx.x * 256 + threadIdx.x;
    if (i < XQ) {
        float4 v = ((const float4*)xf)[i];
        ushort4 o;
        o.x = f2h(v.x); o.y = f2h(v.y); o.z = f2h(v.z); o.w = f2h(v.w);
        ((ushort4*)xb)[i] = o;
    } else {
        int k = i - XQ;
        if (k < WELEMS) {
            int j    = k & 7;
            int lane = (k >> 3) & 63;
            int c    = (k >> 9) & 3;
            int s    = (k >> 11) & 3;
            int lay  = k >> 13;
            int kk = 32 * s + 8 * (lane >> 4) + j;
            int dd = 16 * c + (lane & 15);
            Wperm[k] = f2h(Ws[((size_t)lay * TWO_D + kk) * D + dd]);
        }
    }
}

// 8/4/1-wide fp16 max over [j, end), with next-batch index prefetch.
__device__ __forceinline__ void gather_range(const u16x8* __restrict__ x8,
                                             const int* __restrict__ ssrc,
                                             int fl, int base, int j, int end,
                                             u16x8& m) {
    if (j >= end) return;
    int cnt = min(end - j, 8);
    int idx = ssrc[j + min(fl, cnt - 1)];
    while (true) {
        const int nj = j + cnt;
        const int ncnt = min(end - nj, 8);
        int nidx = 0;
        if (ncnt > 0) nidx = ssrc[nj + min(fl, ncnt - 1)];   // prefetched

        int t = 0;
        if (cnt == 8) {
            int s0 = __shfl(idx, base,     64);
            int s1 = __shfl(idx, base + 1, 64);
            int s2 = __shfl(idx, base + 2, 64);
            int s3 = __shfl(idx, base + 3, 64);
            int s4 = __shfl(idx, base + 4, 64);
            int s5 = __shfl(idx, base + 5, 64);
            int s6 = __shfl(idx, base + 6, 64);
            int s7 = __shfl(idx, base + 7, 64);
            u16x8 r0 = x8[s0 * 8 + fl];
            u16x8 r1 = x8[s1 * 8 + fl];
            u16x8 r2 = x8[s2 * 8 + fl];
            u16x8 r3 = x8[s3 * 8 + fl];
            u16x8 r4 = x8[s4 * 8 + fl];
            u16x8 r5 = x8[s5 * 8 + fl];
            u16x8 r6 = x8[s6 * 8 + fl];
            u16x8 r7 = x8[s7 * 8 + fl];
            m = pkmaxh(m, pkmaxh(pkmaxh(pkmaxh(r0, r1), pkmaxh(r2, r3)),
                                 pkmaxh(pkmaxh(r4, r5), pkmaxh(r6, r7))));
            t = 8;
        }
        if (t + 4 <= cnt) {
            int s0 = __shfl(idx, base + t,     64);
            int s1 = __shfl(idx, base + t + 1, 64);
            int s2 = __shfl(idx, base + t + 2, 64);
            int s3 = __shfl(idx, base + t + 3, 64);
            u16x8 r0 = x8[s0 * 8 + fl];
            u16x8 r1 = x8[s1 * 8 + fl];
            u16x8 r2 = x8[s2 * 8 + fl];
            u16x8 r3 = x8[s3 * 8 + fl];
            m = pkmaxh(m, pkmaxh(pkmaxh(r0, r1), pkmaxh(r2, r3)));
            t += 4;
        }
        for (; t < cnt; ++t) {
            int s0 = __shfl(idx, base + t, 64);
            m = pkmaxh(m, x8[s0 * 8 + fl]);
        }

        if (ncnt <= 0) break;
        j = nj; cnt = ncnt; idx = nidx;
    }
}

// ---------------------------------------------------------------------------
// Fused layer (fp16 domain): 64 nodes per 256-thread block. Each 8-lane group
// gathers a degree-balanced PAIR of node-local ids serially; packed fp16 max;
// agg = max(m - x_dst, 0) in 2 packed ops. x row + agg staged to LDS
// (XOR-swizzled). GEMM: wave per 16 nodes, 16x mfma_f32_16x16x32_f16,
// bias + LayerNorm + ELU epilogue.
// ---------------------------------------------------------------------------
__global__ __launch_bounds__(256) void layer_kernel(
    const ushort* __restrict__ xb,      // fp16 bits
    const int* __restrict__ row_ptr,
    const int* __restrict__ deg,
    const int* __restrict__ ssrc,
    const ushort* __restrict__ pairs,
    const ushort* __restrict__ Wperm,   // this layer's [4][4][64][8] fp16
    const float* __restrict__ bias,
    const float* __restrict__ gamma,
    const float* __restrict__ beta,
    ushort* __restrict__ out_b,         // fp16 out (layers 0,1) or nullptr
    float*  __restrict__ out_f)         // f32 out (layer 2) or nullptr
{
    __shared__ u16x8 xt[64][8];
    __shared__ u16x8 at[64][8];

    const int tid = threadIdx.x;
    const int fl = tid & 7;
    const int base = tid & 56;                 // 8-lane group base within wave
    const int grp = tid >> 3;                  // 0..31
    const u16x8* __restrict__ x8 = (const u16x8*)xb;
    const int nblk0 = blockIdx.x * 64;

    const int pr = pairs[blockIdx.x * 32 + grp];
    const int nls[2] = { pr & 63, (pr >> 6) & 63 };

#pragma unroll
    for (int q = 0; q < 2; ++q) {
        const int nl = nls[q];
        const int node = nblk0 + nl;
        if (node < N_NODES) {
            const u16x8 xs = x8[node * 8 + fl];
            const int beg = row_ptr[node];
            const int end = beg + deg[node];

            u16x8 m;
#pragma unroll
            for (int e = 0; e < 8; ++e) m[e] = 0xFC00;   // -inf fp16
            gather_range(x8, ssrc, fl, base, beg, end, m);

            u16x8 o;
            if (end > beg) {
                h16x8 dd = __builtin_bit_cast(h16x8, m) -
                           __builtin_bit_cast(h16x8, xs);
                h16x8 zz = 0;
                o = __builtin_bit_cast(u16x8, __builtin_elementwise_max(dd, zz));
            } else {
#pragma unroll
                for (int e = 0; e < 8; ++e) o[e] = 0;
            }
            const int slot = fl ^ (nl & 7);
            xt[nl][slot] = xs;
            at[nl][slot] = o;
        }
    }
    __syncthreads();

    // --- GEMM phase: wave per 16 nodes ---
    const int wave = tid >> 6;
    const int lane = tid & 63;
    const int n0 = nblk0 + wave * 16;
    if (n0 >= N_NODES) return;
    const int row = lane & 15;
    const int kb  = lane >> 4;
    const int nl  = wave * 16 + row;
    const int sw  = nl & 7;

    h16x8 a0 = __builtin_bit_cast(h16x8, xt[nl][kb ^ sw]);
    h16x8 a1 = __builtin_bit_cast(h16x8, xt[nl][(kb + 4) ^ sw]);
    h16x8 a2 = __builtin_bit_cast(h16x8, at[nl][kb ^ sw]);
    h16x8 a3 = __builtin_bit_cast(h16x8, at[nl][(kb + 4) ^ sw]);

    const h16x8* __restrict__ wp = (const h16x8*)Wperm;
    h16x8 wf[4][4];
#pragma unroll
    for (int s = 0; s < 4; ++s)
#pragma unroll
        for (int c = 0; c < 4; ++c)
            wf[s][c] = wp[(s * 4 + c) * 64 + lane];

    f32x4 acc[4];
#pragma unroll
    for (int c = 0; c < 4; ++c) acc[c] = (f32x4){0.f, 0.f, 0.f, 0.f};
#pragma unroll
    for (int c = 0; c < 4; ++c) {
        acc[c] = __builtin_amdgcn_mfma_f32_16x16x32_f16(a0, wf[0][c], acc[c], 0, 0, 0);
        acc[c] = __builtin_amdgcn_mfma_f32_16x16x32_f16(a1, wf[1][c], acc[c], 0, 0, 0);
        acc[c] = __builtin_amdgcn_mfma_f32_16x16x32_f16(a2, wf[2][c], acc[c], 0, 0, 0);
        acc[c] = __builtin_amdgcn_mfma_f32_16x16x32_f16(a3, wf[3][c], acc[c], 0, 0, 0);
    }

    float bv[4], gv[4], btv[4];
#pragma unroll
    for (int c = 0; c < 4; ++c) {
        const int col = 16 * c + row;
        bv[c] = bias[col]; gv[c] = gamma[col]; btv[c] = beta[col];
    }

#pragma unroll
    for (int j = 0; j < 4; ++j) {
        float h0 = acc[0][j] + bv[0];
        float h1 = acc[1][j] + bv[1];
        float h2 = acc[2][j] + bv[2];
        float h3 = acc[3][j] + bv[3];
        float ps = (h0 + h1) + (h2 + h3);
        ps += __shfl_xor(ps, 1, 64);
        ps += __shfl_xor(ps, 2, 64);
        ps += __shfl_xor(ps, 4, 64);
        ps += __shfl_xor(ps, 8, 64);
        const float mu = ps * (1.0f / 64.0f);
        const float d0 = h0 - mu, d1 = h1 - mu, d2 = h2 - mu, d3 = h3 - mu;
        float vs = (d0 * d0 + d1 * d1) + (d2 * d2 + d3 * d3);
        vs += __shfl_xor(vs, 1, 64);
        vs += __shfl_xor(vs, 2, 64);
        vs += __shfl_xor(vs, 4, 64);
        vs += __shfl_xor(vs, 8, 64);
        const float rstd = rsqrtf(vs * (1.0f / 64.0f) + LN_EPS);

        const int node = n0 + 4 * kb + j;
        const float dd[4] = {d0, d1, d2, d3};
#pragma unroll
        for (int c = 0; c < 4; ++c) {
            float o = dd[c] * rstd * gv[c] + btv[c];
            o = o > 0.f ? o : expm1f(o);
            if (out_f) out_f[node * D + 16 * c + row] = o;
            else       out_b[node * D + 16 * c + row] = f2h(o);
        }
    }
}

static inline size_t alignup(size_t v) { return (v + 255) & ~(size_t)255; }

extern "C" void kernel_launch(void* const* d_in, const int* in_sizes, int n_in,
                              void* d_out, int out_size, void* d_ws, size_t ws_size,
                              hipStream_t stream) {
    const float* features = (const float*)d_in[0];
    const int*   src      = (const int*)d_in[1];
    const int*   dst      = (const int*)d_in[2];
    const float* Ws       = (const float*)d_in[3];
    const float* bs       = (const float*)d_in[4];
    const float* gammas   = (const float*)d_in[5];
    const float* betas    = (const float*)d_in[6];
    float* out = (float*)d_out;

    char* ws = (char*)d_ws;
    size_t off = 0;
    int* row_ptr = (int*)(ws + off); off = alignup(off + sizeof(int) * N_NODES);
    int* deg     = (int*)(ws + off); off = alignup(off + sizeof(int) * N_NODES);
    int* bofs    = (int*)(ws + off); off = alignup(off + sizeof(int) * (size_t)NEB * BOFS_STRIDE);
    int* ebuf    = (int*)(ws + off); off = alignup(off + sizeof(int) * (size_t)NEB * EPB);
    int* ssrc    = (int*)(ws + off); off = alignup(off + sizeof(int) * (size_t)NBUCK * BCAP);
    ushort* prs  = (ushort*)(ws + off); off = alignup(off + sizeof(ushort) * (size_t)NTILES * 32);
    ushort* xbA  = (ushort*)(ws + off); off = alignup(off + sizeof(ushort) * (size_t)N_NODES * D);
    ushort* xbB  = (ushort*)(ws + off); off = alignup(off + sizeof(ushort) * (size_t)N_NODES * D);
    ushort* Wperm= (ushort*)(ws + off); off = alignup(off + sizeof(ushort) * 3 * TWO_D * D);

    // --- build padded CSR + degree-balanced pairs (once) ---
    bscat_kernel<<<NEB, 1024, 0, stream>>>(src, dst, ebuf, bofs);
    bbuild_kernel<<<NBUCK, 512, 0, stream>>>(ebuf, bofs, row_ptr, deg, ssrc, prs);

    // --- fused converter (x -> fp16, W -> fp16 fragments) ---
    cvt_kernel<<<(XQ + WELEMS + 255) / 256, 256, 0, stream>>>(features, Ws, xbA, Wperm);

    // --- 3 fused layers ---
    ushort* xin = xbA;
    ushort* xnb[3] = { xbB, xbA, nullptr };
    for (int l = 0; l < 3; ++l) {
        layer_kernel<<<NTILES, 256, 0, stream>>>(
            xin, row_ptr, deg, ssrc, prs,
            Wperm + (size_t)l * 16 * 64 * 8,
            bs + (size_t)l * D,
            gammas + (size_t)l * D,
            betas + (size_t)l * D,
            xnb[l],
            (l == 2) ? out : nullptr);
        xin = xnb[l];
    }
}

// Round 12
// 168.258 us; speedup vs baseline: 1.3453x; 1.0638x over previous
//
#include <hip/hip_runtime.h>
#include <hip/hip_bf16.h>
#include <math.h>

#define N_NODES 100000
#define N_EDGES 1600000
#define D 64
#define TWO_D 128
#define LN_EPS 1e-5f

#define BSHIFT 7                                   // 128 nodes per bucket
#define BMASK 127
#define NBUCK ((N_NODES + 127) >> BSHIFT)          // 782
#define BCAP 4096                                  // per-bucket CSR capacity (mean 2046, +45 sigma)
#define EPB 8192                                   // edges per bscat block
#define NEB ((N_EDGES + EPB - 1) / EPB)            // 196
#define BOFS_STRIDE (NBUCK + 1)
#define NTILES ((N_NODES + 63) / 64)               // 1563
#define XQ (N_NODES * D / 4)                       // float4 count for x cvt
#define WELEMS (3 * 4 * 4 * 64 * 8)                // Wperm element count

typedef __attribute__((ext_vector_type(4))) float f32x4;
typedef __attribute__((ext_vector_type(8))) _Float16 h16x8;
typedef __attribute__((ext_vector_type(8))) unsigned short u16x8;

__device__ __forceinline__ unsigned short f2h(float f) {
    return __builtin_bit_cast(unsigned short, (_Float16)f);   // RNE
}
// fp16 packed max on u16 storage (v_pk_max_f16; data is NaN-free).
__device__ __forceinline__ u16x8 pkmaxh(u16x8 a, u16x8 b) {
    return __builtin_bit_cast(u16x8,
        __builtin_elementwise_max(__builtin_bit_cast(h16x8, a),
                                  __builtin_bit_cast(h16x8, b)));
}

// ---------------------------------------------------------------------------
// bscat: per-block FULL LDS sort by bucket; coalesced global writes; no
// global atomics. Emits sorted chunk + per-(block,bucket) exclusive offsets.
// Edge record packed to int32: (src << 7) | (dst & 127); src < 2^17.
// ---------------------------------------------------------------------------
__global__ __launch_bounds__(1024) void bscat_kernel(const int* __restrict__ src,
                                                     const int* __restrict__ dst,
                                                     int* __restrict__ ebuf,
                                                     int* __restrict__ bofs) {
    __shared__ int cnt[NBUCK];
    __shared__ int off[NBUCK];
    __shared__ int stage[EPB];
    const int e0 = blockIdx.x * EPB;
    const int nE = min(EPB, N_EDGES - e0);
    int d[8], s[8];

    for (int i = threadIdx.x; i < NBUCK; i += 1024) cnt[i] = 0;
    __syncthreads();
#pragma unroll
    for (int k = 0; k < 8; ++k) {
        const int i = threadIdx.x + k * 1024;
        if (i < nE) {
            d[k] = dst[e0 + i];
            s[k] = src[e0 + i];
            atomicAdd(&cnt[d[k] >> BSHIFT], 1);
        }
    }
    __syncthreads();
    // Hillis-Steele inclusive scan over NBUCK (<1024)
    const int v = (threadIdx.x < NBUCK) ? cnt[threadIdx.x] : 0;
    if (threadIdx.x < NBUCK) off[threadIdx.x] = v;
    __syncthreads();
    for (int o = 1; o < 1024; o <<= 1) {
        int t = 0;
        if (threadIdx.x < NBUCK && threadIdx.x >= o) t = off[threadIdx.x - o];
        __syncthreads();
        if (threadIdx.x < NBUCK) off[threadIdx.x] += t;
        __syncthreads();
    }
    if (threadIdx.x < NBUCK) {
        const int ex = off[threadIdx.x] - v;      // exclusive
        bofs[blockIdx.x * BOFS_STRIDE + threadIdx.x] = ex;
        off[threadIdx.x] = ex;
        cnt[threadIdx.x] = 0;
    }
    if (threadIdx.x == 0) bofs[blockIdx.x * BOFS_STRIDE + NBUCK] = nE;
    __syncthreads();
#pragma unroll
    for (int k = 0; k < 8; ++k) {
        const int i = threadIdx.x + k * 1024;
        if (i < nE) {
            const int b = d[k] >> BSHIFT;
            const int r = atomicAdd(&cnt[b], 1);
            stage[off[b] + r] = (s[k] << BSHIFT) | (d[k] & BMASK);
        }
    }
    __syncthreads();
    for (int i = threadIdx.x; i < nE; i += 1024)
        ebuf[e0 + i] = stage[i];
}

// ---------------------------------------------------------------------------
// bbuild: one block per bucket (1024 threads). Gathers the bucket's runs from
// all 196 sorted chunks into LDS, counting-sorts by node-within-bucket, emits
// padded CSR + degree-balanced pairs for its two 64-node tiles.
// ---------------------------------------------------------------------------
__global__ __launch_bounds__(1024) void bbuild_kernel(const int* __restrict__ ebuf,
                                                      const int* __restrict__ bofs,
                                                      int* __restrict__ row_ptr,
                                                      int* __restrict__ deg,
                                                      int* __restrict__ ssrc,
                                                      ushort* __restrict__ pairs) {
    __shared__ int rst[NEB], rlen[NEB], rdst[NEB];
    __shared__ int stage[BCAP];
    __shared__ int stage2[BCAP];
    __shared__ int cnt[128], excl[128];
    const int b = blockIdx.x;
    const int nb0 = b << BSHIFT;

    for (int i = threadIdx.x; i < NEB; i += 1024) {
        const int st = bofs[i * BOFS_STRIDE + b];
        const int en = bofs[i * BOFS_STRIDE + b + 1];
        rst[i] = st; rlen[i] = en - st;
    }
    __syncthreads();
    // scan rlen -> rdst (inclusive), NEB=196 < 256
    const int rv = (threadIdx.x < NEB) ? rlen[threadIdx.x] : 0;
    if (threadIdx.x < NEB) rdst[threadIdx.x] = rv;
    __syncthreads();
    for (int o = 1; o < 256; o <<= 1) {
        int t = 0;
        if (threadIdx.x < NEB && threadIdx.x >= o) t = rdst[threadIdx.x - o];
        __syncthreads();
        if (threadIdx.x < NEB) rdst[threadIdx.x] += t;
        __syncthreads();
    }
    const int total = rdst[NEB - 1];

    // gather runs: wave w handles regions w, w+16, ...
    const int wave = threadIdx.x >> 6, lane = threadIdx.x & 63;
    for (int i = wave; i < NEB; i += 16) {
        const int st = rst[i], len = rlen[i], doff = rdst[i] - len;
        for (int l = lane; l < len; l += 64)
            stage[doff + l] = ebuf[i * EPB + st + l];
    }
    if (threadIdx.x < 128) cnt[threadIdx.x] = 0;
    __syncthreads();

    // counting sort by node-within-bucket
    for (int i = threadIdx.x; i < total; i += 1024)
        atomicAdd(&cnt[stage[i] & BMASK], 1);
    __syncthreads();
    const int cv = (threadIdx.x < 128) ? cnt[threadIdx.x] : 0;
    if (threadIdx.x < 128) excl[threadIdx.x] = cv;
    __syncthreads();
    for (int o = 1; o < 128; o <<= 1) {
        int t = 0;
        if (threadIdx.x < 128 && threadIdx.x >= o) t = excl[threadIdx.x - o];
        __syncthreads();
        if (threadIdx.x < 128) excl[threadIdx.x] += t;
        __syncthreads();
    }
    if (threadIdx.x < 128) {
        excl[threadIdx.x] -= cv;              // exclusive
        const int node = nb0 + threadIdx.x;
        if (node < N_NODES) {
            row_ptr[node] = b * BCAP + excl[threadIdx.x];
            deg[node] = cv;
        }
        cnt[threadIdx.x] = 0;
    }

    // fused dbal: bitonic-sort each 64-node tile by degree, pair g <-> 63-g.
    if (threadIdx.x < 128) {
        const int tile = 2 * b + (threadIdx.x >> 6);
        if (tile < NTILES) {
            int key = (cv << 6) | lane;
#pragma unroll
            for (int k = 2; k <= 64; k <<= 1) {
#pragma unroll
                for (int jj = k >> 1; jj > 0; jj >>= 1) {
                    const int other = __shfl_xor(key, jj, 64);
                    const bool up = ((lane & k) == 0);
                    const bool lower = ((lane & jj) == 0);
                    key = (lower == up) ? min(key, other) : max(key, other);
                }
            }
            const int small_nl = key & 63;
            const int big_nl = __shfl(key, 63 - lane, 64) & 63;
            if (lane < 32)
                pairs[tile * 32 + lane] = (ushort)((big_nl << 6) | small_nl);
        }
    }
    __syncthreads();

    for (int i = threadIdx.x; i < total; i += 1024) {
        const int p = stage[i];
        const int dl = p & BMASK;
        const int r = atomicAdd(&cnt[dl], 1);
        stage2[excl[dl] + r] = p >> BSHIFT;
    }
    __syncthreads();
    for (int i = threadIdx.x; i < total; i += 1024)
        ssrc[b * BCAP + i] = stage2[i];
}

// ---------------------------------------------------------------------------
// Fused converter: x (f32 -> fp16) and Wperm (f32 -> fp16, MFMA fragment
// order: Wperm[lay][s][c][lane][j] = W[lay][32s + 8*(lane>>4) + j][16c + (lane&15)])
// ---------------------------------------------------------------------------
__global__ __launch_bounds__(256) void cvt_kernel(const float* __restrict__ xf,
                                                  const float* __restrict__ Ws,
                                                  ushort* __restrict__ xb,
                                                  ushort* __restrict__ Wperm) {
    int i = blockIdx.x * 256 + threadIdx.x;
    if (i < XQ) {
        float4 v = ((const float4*)xf)[i];
        ushort4 o;
        o.x = f2h(v.x); o.y = f2h(v.y); o.z = f2h(v.z); o.w = f2h(v.w);
        ((ushort4*)xb)[i] = o;
    } else {
        int k = i - XQ;
        if (k < WELEMS) {
            int j    = k & 7;
            int lane = (k >> 3) & 63;
            int c    = (k >> 9) & 3;
            int s    = (k >> 11) & 3;
            int lay  = k >> 13;
            int kk = 32 * s + 8 * (lane >> 4) + j;
            int dd = 16 * c + (lane & 15);
            Wperm[k] = f2h(Ws[((size_t)lay * TWO_D + kk) * D + dd]);
        }
    }
}

// ---------------------------------------------------------------------------
// Pipelined gather: 4-row quads, lookahead across quads. Peak 8 rows in
// flight (same VGPR as the old flat batch). Tails are branch-free: edge
// index t clamps to cnt-1 (max is idempotent -> duplicate loads harmless).
// Timeline: [reduce quad-lo overlaps quad-hi flight; next batch's quad-lo
// issues before quad-hi reduce] -> ~1 latency exposure per batch instead of 1
// serial round-trip per batch with dead issue slots.
// ---------------------------------------------------------------------------
__device__ __forceinline__ void gather_node(const u16x8* __restrict__ x8,
                                            const int* __restrict__ ssrc,
                                            int fl, int base, int beg, int end,
                                            u16x8& m) {
    if (beg >= end) return;
    int j = beg;
    int cnt = min(end - j, 8);
    int idx = ssrc[j + min(fl, cnt - 1)];

    int s0 = __shfl(idx, base, 64);
    int s1 = __shfl(idx, base + min(1, cnt - 1), 64);
    int s2 = __shfl(idx, base + min(2, cnt - 1), 64);
    int s3 = __shfl(idx, base + min(3, cnt - 1), 64);
    u16x8 a0 = x8[s0 * 8 + fl];
    u16x8 a1 = x8[s1 * 8 + fl];
    u16x8 a2 = x8[s2 * 8 + fl];
    u16x8 a3 = x8[s3 * 8 + fl];

    while (true) {
        // quad-hi of current batch (clamped duplicates when cnt <= 4)
        int s4 = __shfl(idx, base + min(4, cnt - 1), 64);
        int s5 = __shfl(idx, base + min(5, cnt - 1), 64);
        int s6 = __shfl(idx, base + min(6, cnt - 1), 64);
        int s7 = __shfl(idx, base + min(7, cnt - 1), 64);
        u16x8 b0 = x8[s4 * 8 + fl];
        u16x8 b1 = x8[s5 * 8 + fl];
        u16x8 b2 = x8[s6 * 8 + fl];
        u16x8 b3 = x8[s7 * 8 + fl];

        const int nj = j + cnt;
        const bool more = nj < end;              // group-uniform
        int ncnt = cnt, nidx = idx;
        if (more) {
            ncnt = min(end - nj, 8);
            nidx = ssrc[nj + min(fl, ncnt - 1)]; // prefetched index batch
        }

        m = pkmaxh(m, pkmaxh(pkmaxh(a0, a1), pkmaxh(a2, a3)));   // consume lo

        if (more) {                              // next batch quad-lo in flight
            int u0 = __shfl(nidx, base, 64);
            int u1 = __shfl(nidx, base + min(1, ncnt - 1), 64);
            int u2 = __shfl(nidx, base + min(2, ncnt - 1), 64);
            int u3 = __shfl(nidx, base + min(3, ncnt - 1), 64);
            a0 = x8[u0 * 8 + fl];
            a1 = x8[u1 * 8 + fl];
            a2 = x8[u2 * 8 + fl];
            a3 = x8[u3 * 8 + fl];
        }

        m = pkmaxh(m, pkmaxh(pkmaxh(b0, b1), pkmaxh(b2, b3)));   // consume hi

        if (!more) break;
        j = nj; cnt = ncnt; idx = nidx;
    }
}

// ---------------------------------------------------------------------------
// Fused layer (fp16): 64 nodes per 256-thread block; degree-balanced pairs;
// pipelined gather; MFMA GEMM + bias + LN + ELU. VGPR pinned via
// __launch_bounds__(256, 8) to stay under the 64-VGPR occupancy cliff.
// ---------------------------------------------------------------------------
__global__ __launch_bounds__(256, 8) void layer_kernel(
    const ushort* __restrict__ xb,      // fp16 bits
    const int* __restrict__ row_ptr,
    const int* __restrict__ deg,
    const int* __restrict__ ssrc,
    const ushort* __restrict__ pairs,
    const ushort* __restrict__ Wperm,   // this layer's [4][4][64][8] fp16
    const float* __restrict__ bias,
    const float* __restrict__ gamma,
    const float* __restrict__ beta,
    ushort* __restrict__ out_b,         // fp16 out (layers 0,1) or nullptr
    float*  __restrict__ out_f)         // f32 out (layer 2) or nullptr
{
    __shared__ u16x8 xt[64][8];
    __shared__ u16x8 at[64][8];

    const int tid = threadIdx.x;
    const int fl = tid & 7;
    const int base = tid & 56;                 // 8-lane group base within wave
    const int grp = tid >> 3;                  // 0..31
    const u16x8* __restrict__ x8 = (const u16x8*)xb;
    const int nblk0 = blockIdx.x * 64;

    const int pr = pairs[blockIdx.x * 32 + grp];
    const int nls[2] = { pr & 63, (pr >> 6) & 63 };

#pragma unroll
    for (int q = 0; q < 2; ++q) {
        const int nl = nls[q];
        const int node = nblk0 + nl;
        if (node < N_NODES) {
            const int beg = row_ptr[node];
            const int end = beg + deg[node];

            u16x8 m;
#pragma unroll
            for (int e = 0; e < 8; ++e) m[e] = 0xFC00;   // -inf fp16
            gather_node(x8, ssrc, fl, base, beg, end, m);

            const u16x8 xs = x8[node * 8 + fl];          // load after gather
            u16x8 o;
            if (end > beg) {
                h16x8 dd = __builtin_bit_cast(h16x8, m) -
                           __builtin_bit_cast(h16x8, xs);
                h16x8 zz = 0;
                o = __builtin_bit_cast(u16x8, __builtin_elementwise_max(dd, zz));
            } else {
#pragma unroll
                for (int e = 0; e < 8; ++e) o[e] = 0;
            }
            const int slot = fl ^ (nl & 7);
            xt[nl][slot] = xs;
            at[nl][slot] = o;
        }
    }
    __syncthreads();

    // --- GEMM phase: wave per 16 nodes ---
    const int wave = tid >> 6;
    const int lane = tid & 63;
    const int n0 = nblk0 + wave * 16;
    if (n0 >= N_NODES) return;
    const int row = lane & 15;
    const int kb  = lane >> 4;
    const int nl  = wave * 16 + row;
    const int sw  = nl & 7;

    h16x8 a0 = __builtin_bit_cast(h16x8, xt[nl][kb ^ sw]);
    h16x8 a1 = __builtin_bit_cast(h16x8, xt[nl][(kb + 4) ^ sw]);
    h16x8 a2 = __builtin_bit_cast(h16x8, at[nl][kb ^ sw]);
    h16x8 a3 = __builtin_bit_cast(h16x8, at[nl][(kb + 4) ^ sw]);

    const h16x8* __restrict__ wp = (const h16x8*)Wperm;
    h16x8 wf[4][4];
#pragma unroll
    for (int s = 0; s < 4; ++s)
#pragma unroll
        for (int c = 0; c < 4; ++c)
            wf[s][c] = wp[(s * 4 + c) * 64 + lane];

    f32x4 acc[4];
#pragma unroll
    for (int c = 0; c < 4; ++c) acc[c] = (f32x4){0.f, 0.f, 0.f, 0.f};
#pragma unroll
    for (int c = 0; c < 4; ++c) {
        acc[c] = __builtin_amdgcn_mfma_f32_16x16x32_f16(a0, wf[0][c], acc[c], 0, 0, 0);
        acc[c] = __builtin_amdgcn_mfma_f32_16x16x32_f16(a1, wf[1][c], acc[c], 0, 0, 0);
        acc[c] = __builtin_amdgcn_mfma_f32_16x16x32_f16(a2, wf[2][c], acc[c], 0, 0, 0);
        acc[c] = __builtin_amdgcn_mfma_f32_16x16x32_f16(a3, wf[3][c], acc[c], 0, 0, 0);
    }

    float bv[4], gv[4], btv[4];
#pragma unroll
    for (int c = 0; c < 4; ++c) {
        const int col = 16 * c + row;
        bv[c] = bias[col]; gv[c] = gamma[col]; btv[c] = beta[col];
    }

#pragma unroll
    for (int j = 0; j < 4; ++j) {
        float h0 = acc[0][j] + bv[0];
        float h1 = acc[1][j] + bv[1];
        float h2 = acc[2][j] + bv[2];
        float h3 = acc[3][j] + bv[3];
        float ps = (h0 + h1) + (h2 + h3);
        ps += __shfl_xor(ps, 1, 64);
        ps += __shfl_xor(ps, 2, 64);
        ps += __shfl_xor(ps, 4, 64);
        ps += __shfl_xor(ps, 8, 64);
        const float mu = ps * (1.0f / 64.0f);
        const float d0 = h0 - mu, d1 = h1 - mu, d2 = h2 - mu, d3 = h3 - mu;
        float vs = (d0 * d0 + d1 * d1) + (d2 * d2 + d3 * d3);
        vs += __shfl_xor(vs, 1, 64);
        vs += __shfl_xor(vs, 2, 64);
        vs += __shfl_xor(vs, 4, 64);
        vs += __shfl_xor(vs, 8, 64);
        const float rstd = rsqrtf(vs * (1.0f / 64.0f) + LN_EPS);

        const int node = n0 + 4 * kb + j;
        const float dd[4] = {d0, d1, d2, d3};
#pragma unroll
        for (int c = 0; c < 4; ++c) {
            float o = dd[c] * rstd * gv[c] + btv[c];
            o = o > 0.f ? o : expm1f(o);
            if (out_f) out_f[node * D + 16 * c + row] = o;
            else       out_b[node * D + 16 * c + row] = f2h(o);
        }
    }
}

static inline size_t alignup(size_t v) { return (v + 255) & ~(size_t)255; }

extern "C" void kernel_launch(void* const* d_in, const int* in_sizes, int n_in,
                              void* d_out, int out_size, void* d_ws, size_t ws_size,
                              hipStream_t stream) {
    const float* features = (const float*)d_in[0];
    const int*   src      = (const int*)d_in[1];
    const int*   dst      = (const int*)d_in[2];
    const float* Ws       = (const float*)d_in[3];
    const float* bs       = (const float*)d_in[4];
    const float* gammas   = (const float*)d_in[5];
    const float* betas    = (const float*)d_in[6];
    float* out = (float*)d_out;

    char* ws = (char*)d_ws;
    size_t off = 0;
    int* row_ptr = (int*)(ws + off); off = alignup(off + sizeof(int) * N_NODES);
    int* deg     = (int*)(ws + off); off = alignup(off + sizeof(int) * N_NODES);
    int* bofs    = (int*)(ws + off); off = alignup(off + sizeof(int) * (size_t)NEB * BOFS_STRIDE);
    int* ebuf    = (int*)(ws + off); off = alignup(off + sizeof(int) * (size_t)NEB * EPB);
    int* ssrc    = (int*)(ws + off); off = alignup(off + sizeof(int) * (size_t)NBUCK * BCAP);
    ushort* prs  = (ushort*)(ws + off); off = alignup(off + sizeof(ushort) * (size_t)NTILES * 32);
    ushort* xbA  = (ushort*)(ws + off); off = alignup(off + sizeof(ushort) * (size_t)N_NODES * D);
    ushort* xbB  = (ushort*)(ws + off); off = alignup(off + sizeof(ushort) * (size_t)N_NODES * D);
    ushort* Wperm= (ushort*)(ws + off); off = alignup(off + sizeof(ushort) * 3 * TWO_D * D);

    // --- build padded CSR + degree-balanced pairs (once) ---
    bscat_kernel<<<NEB, 1024, 0, stream>>>(src, dst, ebuf, bofs);
    bbuild_kernel<<<NBUCK, 1024, 0, stream>>>(ebuf, bofs, row_ptr, deg, ssrc, prs);

    // --- fused converter (x -> fp16, W -> fp16 fragments) ---
    cvt_kernel<<<(XQ + WELEMS + 255) / 256, 256, 0, stream>>>(features, Ws, xbA, Wperm);

    // --- 3 fused layers ---
    ushort* xin = xbA;
    ushort* xnb[3] = { xbB, xbA, nullptr };
    for (int l = 0; l < 3; ++l) {
        layer_kernel<<<NTILES, 256, 0, stream>>>(
            xin, row_ptr, deg, ssrc, prs,
            Wperm + (size_t)l * 16 * 64 * 8,
            bs + (size_t)l * D,
            gammas + (size_t)l * D,
            betas + (size_t)l * D,
            xnb[l],
            (l == 2) ? out : nullptr);
        xin = xnb[l];
    }
}

// Round 13
// 140.758 us; speedup vs baseline: 1.6082x; 1.1954x over previous
//
#include <hip/hip_runtime.h>
#include <hip/hip_bf16.h>
#include <math.h>

#define N_NODES 100000
#define N_EDGES 1600000
#define D 64
#define TWO_D 128
#define LN_EPS 1e-5f

#define BSHIFT 7                                   // 128 nodes per bucket
#define BMASK 127
#define NBUCK ((N_NODES + 127) >> BSHIFT)          // 782
#define BCAP 4096                                  // per-bucket CSR capacity (mean 2046, +45 sigma)
#define EPB 8192                                   // edges per bscat block
#define NEB ((N_EDGES + EPB - 1) / EPB)            // 196
#define BOFS_STRIDE (NBUCK + 1)
#define NTILES ((N_NODES + 63) / 64)               // 1563
#define XQ (N_NODES * D / 4)                       // float4 count for x cvt
#define WELEMS (3 * 4 * 4 * 64 * 8)                // Wperm element count

typedef __attribute__((ext_vector_type(4))) float f32x4;
typedef __attribute__((ext_vector_type(8))) _Float16 h16x8;
typedef __attribute__((ext_vector_type(8))) unsigned short u16x8;

__device__ __forceinline__ unsigned short f2h(float f) {
    return __builtin_bit_cast(unsigned short, (_Float16)f);   // RNE
}
// fp16 packed max on u16 storage (v_pk_max_f16; data is NaN-free).
__device__ __forceinline__ u16x8 pkmaxh(u16x8 a, u16x8 b) {
    return __builtin_bit_cast(u16x8,
        __builtin_elementwise_max(__builtin_bit_cast(h16x8, a),
                                  __builtin_bit_cast(h16x8, b)));
}

// ---------------------------------------------------------------------------
// bscat: per-block FULL LDS sort by bucket; coalesced global writes; no
// global atomics. Emits sorted chunk + per-(block,bucket) exclusive offsets.
// Edge record packed to int32: (src << 7) | (dst & 127); src < 2^17.
// ---------------------------------------------------------------------------
__global__ __launch_bounds__(1024) void bscat_kernel(const int* __restrict__ src,
                                                     const int* __restrict__ dst,
                                                     int* __restrict__ ebuf,
                                                     int* __restrict__ bofs) {
    __shared__ int cnt[NBUCK];
    __shared__ int off[NBUCK];
    __shared__ int stage[EPB];
    const int e0 = blockIdx.x * EPB;
    const int nE = min(EPB, N_EDGES - e0);
    int d[8], s[8];

    for (int i = threadIdx.x; i < NBUCK; i += 1024) cnt[i] = 0;
    __syncthreads();
#pragma unroll
    for (int k = 0; k < 8; ++k) {
        const int i = threadIdx.x + k * 1024;
        if (i < nE) {
            d[k] = dst[e0 + i];
            s[k] = src[e0 + i];
            atomicAdd(&cnt[d[k] >> BSHIFT], 1);
        }
    }
    __syncthreads();
    // Hillis-Steele inclusive scan over NBUCK (<1024)
    const int v = (threadIdx.x < NBUCK) ? cnt[threadIdx.x] : 0;
    if (threadIdx.x < NBUCK) off[threadIdx.x] = v;
    __syncthreads();
    for (int o = 1; o < 1024; o <<= 1) {
        int t = 0;
        if (threadIdx.x < NBUCK && threadIdx.x >= o) t = off[threadIdx.x - o];
        __syncthreads();
        if (threadIdx.x < NBUCK) off[threadIdx.x] += t;
        __syncthreads();
    }
    if (threadIdx.x < NBUCK) {
        const int ex = off[threadIdx.x] - v;      // exclusive
        bofs[blockIdx.x * BOFS_STRIDE + threadIdx.x] = ex;
        off[threadIdx.x] = ex;
        cnt[threadIdx.x] = 0;
    }
    if (threadIdx.x == 0) bofs[blockIdx.x * BOFS_STRIDE + NBUCK] = nE;
    __syncthreads();
#pragma unroll
    for (int k = 0; k < 8; ++k) {
        const int i = threadIdx.x + k * 1024;
        if (i < nE) {
            const int b = d[k] >> BSHIFT;
            const int r = atomicAdd(&cnt[b], 1);
            stage[off[b] + r] = (s[k] << BSHIFT) | (d[k] & BMASK);
        }
    }
    __syncthreads();
    for (int i = threadIdx.x; i < nE; i += 1024)
        ebuf[e0 + i] = stage[i];
}

// ---------------------------------------------------------------------------
// bbuild: one block per bucket (512 threads). DENSE run gather: each thread
// owns output positions pos, pos+512, ... and binary-searches rdst[] to find
// its run -> all ~2046 loads in flight across the block (was: wave-per-run
// serial, ~16% lane-active). Then LDS counting sort -> padded CSR + pairs.
// ---------------------------------------------------------------------------
__global__ __launch_bounds__(512) void bbuild_kernel(const int* __restrict__ ebuf,
                                                     const int* __restrict__ bofs,
                                                     int* __restrict__ row_ptr,
                                                     int* __restrict__ deg,
                                                     int* __restrict__ ssrc,
                                                     ushort* __restrict__ pairs) {
    __shared__ int rst[NEB], rlen[NEB], rdst[NEB];
    __shared__ int stage[BCAP];
    __shared__ int stage2[BCAP];
    __shared__ int cnt[128], excl[128];
    const int b = blockIdx.x;
    const int nb0 = b << BSHIFT;

    for (int i = threadIdx.x; i < NEB; i += 512) {
        const int st = bofs[i * BOFS_STRIDE + b];
        const int en = bofs[i * BOFS_STRIDE + b + 1];
        rst[i] = st; rlen[i] = en - st;
    }
    __syncthreads();
    // scan rlen -> rdst (inclusive), NEB=196 < 256
    const int rv = (threadIdx.x < NEB) ? rlen[threadIdx.x] : 0;
    if (threadIdx.x < NEB) rdst[threadIdx.x] = rv;
    __syncthreads();
    for (int o = 1; o < 256; o <<= 1) {
        int t = 0;
        if (threadIdx.x < NEB && threadIdx.x >= o) t = rdst[threadIdx.x - o];
        __syncthreads();
        if (threadIdx.x < NEB) rdst[threadIdx.x] += t;
        __syncthreads();
    }
    const int total = rdst[NEB - 1];

    // dense gather: binary search run for each output position
    for (int pos = threadIdx.x; pos < total; pos += 512) {
        int lo = 0, hi = NEB - 1;
        while (lo < hi) {                       // first run with rdst[run] > pos
            const int mid = (lo + hi) >> 1;
            if (rdst[mid] <= pos) lo = mid + 1; else hi = mid;
        }
        const int doff = rdst[lo] - rlen[lo];
        stage[pos] = ebuf[lo * EPB + rst[lo] + (pos - doff)];
    }
    if (threadIdx.x < 128) cnt[threadIdx.x] = 0;
    __syncthreads();

    // counting sort by node-within-bucket
    for (int i = threadIdx.x; i < total; i += 512)
        atomicAdd(&cnt[stage[i] & BMASK], 1);
    __syncthreads();
    const int cv = (threadIdx.x < 128) ? cnt[threadIdx.x] : 0;
    if (threadIdx.x < 128) excl[threadIdx.x] = cv;
    __syncthreads();
    for (int o = 1; o < 128; o <<= 1) {
        int t = 0;
        if (threadIdx.x < 128 && threadIdx.x >= o) t = excl[threadIdx.x - o];
        __syncthreads();
        if (threadIdx.x < 128) excl[threadIdx.x] += t;
        __syncthreads();
    }
    const int lane = threadIdx.x & 63;
    if (threadIdx.x < 128) {
        excl[threadIdx.x] -= cv;              // exclusive
        const int node = nb0 + threadIdx.x;
        if (node < N_NODES) {
            row_ptr[node] = b * BCAP + excl[threadIdx.x];
            deg[node] = cv;
        }
        cnt[threadIdx.x] = 0;
    }

    // fused dbal: bitonic-sort each 64-node tile by degree, pair g <-> 63-g.
    if (threadIdx.x < 128) {
        const int tile = 2 * b + (threadIdx.x >> 6);
        if (tile < NTILES) {
            int key = (cv << 6) | lane;
#pragma unroll
            for (int k = 2; k <= 64; k <<= 1) {
#pragma unroll
                for (int jj = k >> 1; jj > 0; jj >>= 1) {
                    const int other = __shfl_xor(key, jj, 64);
                    const bool up = ((lane & k) == 0);
                    const bool lower = ((lane & jj) == 0);
                    key = (lower == up) ? min(key, other) : max(key, other);
                }
            }
            const int small_nl = key & 63;
            const int big_nl = __shfl(key, 63 - lane, 64) & 63;
            if (lane < 32)
                pairs[tile * 32 + lane] = (ushort)((big_nl << 6) | small_nl);
        }
    }
    __syncthreads();

    for (int i = threadIdx.x; i < total; i += 512) {
        const int p = stage[i];
        const int dl = p & BMASK;
        const int r = atomicAdd(&cnt[dl], 1);
        stage2[excl[dl] + r] = p >> BSHIFT;
    }
    __syncthreads();
    for (int i = threadIdx.x; i < total; i += 512)
        ssrc[b * BCAP + i] = stage2[i];
}

// ---------------------------------------------------------------------------
// Fused converter: x (f32 -> fp16) and Wperm (f32 -> fp16, MFMA fragment
// order: Wperm[lay][s][c][lane][j] = W[lay][32s + 8*(lane>>4) + j][16c + (lane&15)])
// ---------------------------------------------------------------------------
__global__ __launch_bounds__(256) void cvt_kernel(const float* __restrict__ xf,
                                                  const float* __restrict__ Ws,
                                                  ushort* __restrict__ xb,
                                                  ushort* __restrict__ Wperm) {
    int i = blockIdx.x * 256 + threadIdx.x;
    if (i < XQ) {
        float4 v = ((const float4*)xf)[i];
        ushort4 o;
        o.x = f2h(v.x); o.y = f2h(v.y); o.z = f2h(v.z); o.w = f2h(v.w);
        ((ushort4*)xb)[i] = o;
    } else {
        int k = i - XQ;
        if (k < WELEMS) {
            int j    = k & 7;
            int lane = (k >> 3) & 63;
            int c    = (k >> 9) & 3;
            int s    = (k >> 11) & 3;
            int lay  = k >> 13;
            int kk = 32 * s + 8 * (lane >> 4) + j;
            int dd = 16 * c + (lane & 15);
            Wperm[k] = f2h(Ws[((size_t)lay * TWO_D + kk) * D + dd]);
        }
    }
}

// ---------------------------------------------------------------------------
// Pipelined gather: 4-row quads, lookahead across quads. Peak 8 rows in
// flight. Tails branch-free: edge index clamps to cnt-1 (max idempotent).
// ---------------------------------------------------------------------------
__device__ __forceinline__ void gather_node(const u16x8* __restrict__ x8,
                                            const int* __restrict__ ssrc,
                                            int fl, int base, int beg, int end,
                                            u16x8& m) {
    if (beg >= end) return;
    int j = beg;
    int cnt = min(end - j, 8);
    int idx = ssrc[j + min(fl, cnt - 1)];

    int s0 = __shfl(idx, base, 64);
    int s1 = __shfl(idx, base + min(1, cnt - 1), 64);
    int s2 = __shfl(idx, base + min(2, cnt - 1), 64);
    int s3 = __shfl(idx, base + min(3, cnt - 1), 64);
    u16x8 a0 = x8[s0 * 8 + fl];
    u16x8 a1 = x8[s1 * 8 + fl];
    u16x8 a2 = x8[s2 * 8 + fl];
    u16x8 a3 = x8[s3 * 8 + fl];

    while (true) {
        // quad-hi of current batch (clamped duplicates when cnt <= 4)
        int s4 = __shfl(idx, base + min(4, cnt - 1), 64);
        int s5 = __shfl(idx, base + min(5, cnt - 1), 64);
        int s6 = __shfl(idx, base + min(6, cnt - 1), 64);
        int s7 = __shfl(idx, base + min(7, cnt - 1), 64);
        u16x8 b0 = x8[s4 * 8 + fl];
        u16x8 b1 = x8[s5 * 8 + fl];
        u16x8 b2 = x8[s6 * 8 + fl];
        u16x8 b3 = x8[s7 * 8 + fl];

        const int nj = j + cnt;
        const bool more = nj < end;              // group-uniform
        int ncnt = cnt, nidx = idx;
        if (more) {
            ncnt = min(end - nj, 8);
            nidx = ssrc[nj + min(fl, ncnt - 1)]; // prefetched index batch
        }

        m = pkmaxh(m, pkmaxh(pkmaxh(a0, a1), pkmaxh(a2, a3)));   // consume lo

        if (more) {                              // next batch quad-lo in flight
            int u0 = __shfl(nidx, base, 64);
            int u1 = __shfl(nidx, base + min(1, ncnt - 1), 64);
            int u2 = __shfl(nidx, base + min(2, ncnt - 1), 64);
            int u3 = __shfl(nidx, base + min(3, ncnt - 1), 64);
            a0 = x8[u0 * 8 + fl];
            a1 = x8[u1 * 8 + fl];
            a2 = x8[u2 * 8 + fl];
            a3 = x8[u3 * 8 + fl];
        }

        m = pkmaxh(m, pkmaxh(pkmaxh(b0, b1), pkmaxh(b2, b3)));   // consume hi

        if (!more) break;
        j = nj; cnt = ncnt; idx = nidx;
    }
}

// ---------------------------------------------------------------------------
// Fused layer (fp16): 64 nodes per 256-thread block; degree-balanced pairs;
// pipelined gather; MFMA GEMM + bias + LN + ELU.
// ---------------------------------------------------------------------------
__global__ __launch_bounds__(256, 8) void layer_kernel(
    const ushort* __restrict__ xb,      // fp16 bits
    const int* __restrict__ row_ptr,
    const int* __restrict__ deg,
    const int* __restrict__ ssrc,
    const ushort* __restrict__ pairs,
    const ushort* __restrict__ Wperm,   // this layer's [4][4][64][8] fp16
    const float* __restrict__ bias,
    const float* __restrict__ gamma,
    const float* __restrict__ beta,
    ushort* __restrict__ out_b,         // fp16 out (layers 0,1) or nullptr
    float*  __restrict__ out_f)         // f32 out (layer 2) or nullptr
{
    __shared__ u16x8 xt[64][8];
    __shared__ u16x8 at[64][8];

    const int tid = threadIdx.x;
    const int fl = tid & 7;
    const int base = tid & 56;                 // 8-lane group base within wave
    const int grp = tid >> 3;                  // 0..31
    const u16x8* __restrict__ x8 = (const u16x8*)xb;
    const int nblk0 = blockIdx.x * 64;

    const int pr = pairs[blockIdx.x * 32 + grp];
    const int nls[2] = { pr & 63, (pr >> 6) & 63 };

#pragma unroll
    for (int q = 0; q < 2; ++q) {
        const int nl = nls[q];
        const int node = nblk0 + nl;
        if (node < N_NODES) {
            const int beg = row_ptr[node];
            const int end = beg + deg[node];

            u16x8 m;
#pragma unroll
            for (int e = 0; e < 8; ++e) m[e] = 0xFC00;   // -inf fp16
            gather_node(x8, ssrc, fl, base, beg, end, m);

            const u16x8 xs = x8[node * 8 + fl];          // load after gather
            u16x8 o;
            if (end > beg) {
                h16x8 dd = __builtin_bit_cast(h16x8, m) -
                           __builtin_bit_cast(h16x8, xs);
                h16x8 zz = 0;
                o = __builtin_bit_cast(u16x8, __builtin_elementwise_max(dd, zz));
            } else {
#pragma unroll
                for (int e = 0; e < 8; ++e) o[e] = 0;
            }
            const int slot = fl ^ (nl & 7);
            xt[nl][slot] = xs;
            at[nl][slot] = o;
        }
    }
    __syncthreads();

    // --- GEMM phase: wave per 16 nodes ---
    const int wave = tid >> 6;
    const int lane = tid & 63;
    const int n0 = nblk0 + wave * 16;
    if (n0 >= N_NODES) return;
    const int row = lane & 15;
    const int kb  = lane >> 4;
    const int nl  = wave * 16 + row;
    const int sw  = nl & 7;

    h16x8 a0 = __builtin_bit_cast(h16x8, xt[nl][kb ^ sw]);
    h16x8 a1 = __builtin_bit_cast(h16x8, xt[nl][(kb + 4) ^ sw]);
    h16x8 a2 = __builtin_bit_cast(h16x8, at[nl][kb ^ sw]);
    h16x8 a3 = __builtin_bit_cast(h16x8, at[nl][(kb + 4) ^ sw]);

    const h16x8* __restrict__ wp = (const h16x8*)Wperm;
    h16x8 wf[4][4];
#pragma unroll
    for (int s = 0; s < 4; ++s)
#pragma unroll
        for (int c = 0; c < 4; ++c)
            wf[s][c] = wp[(s * 4 + c) * 64 + lane];

    f32x4 acc[4];
#pragma unroll
    for (int c = 0; c < 4; ++c) acc[c] = (f32x4){0.f, 0.f, 0.f, 0.f};
#pragma unroll
    for (int c = 0; c < 4; ++c) {
        acc[c] = __builtin_amdgcn_mfma_f32_16x16x32_f16(a0, wf[0][c], acc[c], 0, 0, 0);
        acc[c] = __builtin_amdgcn_mfma_f32_16x16x32_f16(a1, wf[1][c], acc[c], 0, 0, 0);
        acc[c] = __builtin_amdgcn_mfma_f32_16x16x32_f16(a2, wf[2][c], acc[c], 0, 0, 0);
        acc[c] = __builtin_amdgcn_mfma_f32_16x16x32_f16(a3, wf[3][c], acc[c], 0, 0, 0);
    }

    float bv[4], gv[4], btv[4];
#pragma unroll
    for (int c = 0; c < 4; ++c) {
        const int col = 16 * c + row;
        bv[c] = bias[col]; gv[c] = gamma[col]; btv[c] = beta[col];
    }

#pragma unroll
    for (int j = 0; j < 4; ++j) {
        float h0 = acc[0][j] + bv[0];
        float h1 = acc[1][j] + bv[1];
        float h2 = acc[2][j] + bv[2];
        float h3 = acc[3][j] + bv[3];
        float ps = (h0 + h1) + (h2 + h3);
        ps += __shfl_xor(ps, 1, 64);
        ps += __shfl_xor(ps, 2, 64);
        ps += __shfl_xor(ps, 4, 64);
        ps += __shfl_xor(ps, 8, 64);
        const float mu = ps * (1.0f / 64.0f);
        const float d0 = h0 - mu, d1 = h1 - mu, d2 = h2 - mu, d3 = h3 - mu;
        float vs = (d0 * d0 + d1 * d1) + (d2 * d2 + d3 * d3);
        vs += __shfl_xor(vs, 1, 64);
        vs += __shfl_xor(vs, 2, 64);
        vs += __shfl_xor(vs, 4, 64);
        vs += __shfl_xor(vs, 8, 64);
        const float rstd = rsqrtf(vs * (1.0f / 64.0f) + LN_EPS);

        const int node = n0 + 4 * kb + j;
        const float dd[4] = {d0, d1, d2, d3};
#pragma unroll
        for (int c = 0; c < 4; ++c) {
            float o = dd[c] * rstd * gv[c] + btv[c];
            o = o > 0.f ? o : expm1f(o);
            if (out_f) out_f[node * D + 16 * c + row] = o;
            else       out_b[node * D + 16 * c + row] = f2h(o);
        }
    }
}

static inline size_t alignup(size_t v) { return (v + 255) & ~(size_t)255; }

extern "C" void kernel_launch(void* const* d_in, const int* in_sizes, int n_in,
                              void* d_out, int out_size, void* d_ws, size_t ws_size,
                              hipStream_t stream) {
    const float* features = (const float*)d_in[0];
    const int*   src      = (const int*)d_in[1];
    const int*   dst      = (const int*)d_in[2];
    const float* Ws       = (const float*)d_in[3];
    const float* bs       = (const float*)d_in[4];
    const float* gammas   = (const float*)d_in[5];
    const float* betas    = (const float*)d_in[6];
    float* out = (float*)d_out;

    char* ws = (char*)d_ws;
    size_t off = 0;
    int* row_ptr = (int*)(ws + off); off = alignup(off + sizeof(int) * N_NODES);
    int* deg     = (int*)(ws + off); off = alignup(off + sizeof(int) * N_NODES);
    int* bofs    = (int*)(ws + off); off = alignup(off + sizeof(int) * (size_t)NEB * BOFS_STRIDE);
    int* ebuf    = (int*)(ws + off); off = alignup(off + sizeof(int) * (size_t)NEB * EPB);
    int* ssrc    = (int*)(ws + off); off = alignup(off + sizeof(int) * (size_t)NBUCK * BCAP);
    ushort* prs  = (ushort*)(ws + off); off = alignup(off + sizeof(ushort) * (size_t)NTILES * 32);
    ushort* xbA  = (ushort*)(ws + off); off = alignup(off + sizeof(ushort) * (size_t)N_NODES * D);
    ushort* xbB  = (ushort*)(ws + off); off = alignup(off + sizeof(ushort) * (size_t)N_NODES * D);
    ushort* Wperm= (ushort*)(ws + off); off = alignup(off + sizeof(ushort) * 3 * TWO_D * D);

    // --- build padded CSR + degree-balanced pairs (once) ---
    bscat_kernel<<<NEB, 1024, 0, stream>>>(src, dst, ebuf, bofs);
    bbuild_kernel<<<NBUCK, 512, 0, stream>>>(ebuf, bofs, row_ptr, deg, ssrc, prs);

    // --- fused converter (x -> fp16, W -> fp16 fragments) ---
    cvt_kernel<<<(XQ + WELEMS + 255) / 256, 256, 0, stream>>>(features, Ws, xbA, Wperm);

    // --- 3 fused layers ---
    ushort* xin = xbA;
    ushort* xnb[3] = { xbB, xbA, nullptr };
    for (int l = 0; l < 3; ++l) {
        layer_kernel<<<NTILES, 256, 0, stream>>>(
            xin, row_ptr, deg, ssrc, prs,
            Wperm + (size_t)l * 16 * 64 * 8,
            bs + (size_t)l * D,
            gammas + (size_t)l * D,
            betas + (size_t)l * D,
            xnb[l],
            (l == 2) ? out : nullptr);
        xin = xnb[l];
    }
}